// Round 4
// baseline (5519.348 us; speedup 1.0000x reference)
//
#include <hip/hip_runtime.h>
#include <hip/hip_bf16.h>
#include <math.h>

// ---------------- problem constants ----------------
// x: (4,512,50,50) f32; conv1_w: (512,512,3,3); heads: 36 loc + 18 score ch
// outputs (f32, concat): rpn_locs 360000 | rpn_scores 180000 @360000 |
//   rois 4800 @540000 | roi_indices 1200 @544800 | anchor 90000 @546000
//
// Numerics: proposal path in f64 end-to-end (reference "ref=np" is float64;
// f64 makes every discrete decision — top-k order, IoU>0.7, min-size —
// deterministic to ~1e-12 margins).
// R4 FIX: heads_kernel pixel range is [0,2500) per image (was 10000 —
// OOB writes corrupted scoreD + raced across images; root cause of the
// precision-independent rois failure in R0-R3).

#define CONV_ICH 8

// ======================= conv 3x3 + bias + relu (f64 accumulate) ============
__global__ __launch_bounds__(256) void conv3x3_kernel(
    const float* __restrict__ xg, const float* __restrict__ wg,
    const float* __restrict__ bg, double* __restrict__ featD)
{
  const int ygrp = blockIdx.x, ocb = blockIdx.y, n = blockIdx.z;
  const int t = threadIdx.x;
  const int tx = t & 15;      // x = tx*4 + xi
  const int toc = t >> 4;     // oc = oc0 + toc*4 + j
  const int y0 = ygrp * 2;
  const int oc0 = ocb * 64;

  __shared__ __align__(16) float sIn[CONV_ICH * 4 * 52];  // [ic][row(4)][52]
  __shared__ __align__(16) float sW[72 * 68];             // [ic*9+k][oc(64), pad 68]

  double acc[2][4][4];
  #pragma unroll
  for (int a = 0; a < 2; a++)
    #pragma unroll
    for (int b = 0; b < 4; b++)
      #pragma unroll
      for (int c = 0; c < 4; c++) acc[a][b][c] = 0.0;

  for (int chunk = 0; chunk < 512 / CONV_ICH; ++chunk) {
    const int ic0 = chunk * CONV_ICH;
    __syncthreads();
    for (int e = t; e < CONV_ICH * 4 * 52; e += 256) {
      int ic = e / 208;
      int rem = e - ic * 208;
      int r = rem / 52;
      int xx = rem - r * 52;
      int yy = y0 + r - 1;
      int xc = xx - 1;
      float v = 0.f;
      if (yy >= 0 && yy < 50 && xc >= 0 && xc < 50)
        v = xg[(((size_t)n * 512 + ic0 + ic) * 50 + yy) * 50 + xc];
      sIn[e] = v;
    }
    for (int e = t; e < 64 * CONV_ICH * 9; e += 256) {
      int oc = e / 72;
      int r = e - oc * 72;
      sW[r * 68 + oc] = wg[((size_t)(oc0 + oc) * 512 + ic0) * 9 + r];
    }
    __syncthreads();

    for (int icl = 0; icl < CONV_ICH; ++icl) {
      double rows[4][6];
      #pragma unroll
      for (int r = 0; r < 4; r++) {
        const float* pb = &sIn[icl * 208 + r * 52 + tx * 4];
        float4 a4 = *(const float4*)pb;
        float2 b2 = *(const float2*)(pb + 4);
        rows[r][0] = (double)a4.x; rows[r][1] = (double)a4.y;
        rows[r][2] = (double)a4.z; rows[r][3] = (double)a4.w;
        rows[r][4] = (double)b2.x; rows[r][5] = (double)b2.y;
      }
      #pragma unroll
      for (int k = 0; k < 9; k++) {
        const int ky = k / 3, kx = k - ky * 3;
        float4 wv = *(const float4*)&sW[(icl * 9 + k) * 68 + toc * 4];
        double wa[4] = {(double)wv.x, (double)wv.y, (double)wv.z, (double)wv.w};
        #pragma unroll
        for (int j = 0; j < 4; j++)
          #pragma unroll
          for (int yy = 0; yy < 2; yy++)
            #pragma unroll
            for (int xi = 0; xi < 4; xi++)
              acc[yy][j][xi] += wa[j] * rows[yy + ky][xi + kx];
      }
    }
  }
  #pragma unroll
  for (int j = 0; j < 4; j++) {
    const int oc = oc0 + toc * 4 + j;
    const double bias = (double)bg[oc];
    #pragma unroll
    for (int yy = 0; yy < 2; yy++) {
      const int y = y0 + yy;
      size_t rowbase = (((size_t)n * 512 + oc) * 50 + y) * 50;
      int xb = tx * 4;
      if (xb < 50) {
        int lim = (xb + 3 < 50) ? 4 : 2;   // xb==48 -> only 2 valid
        #pragma unroll
        for (int xi = 0; xi < 4; xi++) {
          if (xi < lim)
            featD[rowbase + xb + xi] = fmax(acc[yy][j][xi] + bias, 0.0);
        }
      }
    }
  }
}

// ======================= 1x1 heads (loc 36 + score 18), f64 =================
// p = PIXEL index in [0, 2500) per image (batch is blockIdx.z).
__global__ __launch_bounds__(256) void heads_kernel(
    const double* __restrict__ featD,
    const float* __restrict__ loc_w, const float* __restrict__ loc_b,
    const float* __restrict__ score_w, const float* __restrict__ score_b,
    double* __restrict__ locD, double* __restrict__ scoreD,
    float* __restrict__ out)
{
  const int p = blockIdx.x * 256 + threadIdx.x;
  const int ocg = blockIdx.y;
  const int n = blockIdx.z;
  const bool pv = (p < 2500);          // R4 FIX (was 10000)
  const int pp = pv ? p : 0;
  const double* fbase = featD + (size_t)n * 512 * 2500 + pp;

  const float* wr[8];
  double bias[8];
  #pragma unroll
  for (int jj = 0; jj < 8; jj++) {
    int oc = ocg * 8 + jj;
    int occ = (oc < 54) ? oc : 0;
    if (occ < 36) { wr[jj] = loc_w + (size_t)occ * 512; bias[jj] = (double)loc_b[occ]; }
    else { wr[jj] = score_w + (size_t)(occ - 36) * 512; bias[jj] = (double)score_b[occ - 36]; }
  }
  double acc[8] = {0, 0, 0, 0, 0, 0, 0, 0};
  for (int c = 0; c < 512; c++) {
    double f = fbase[(size_t)c * 2500];
    #pragma unroll
    for (int jj = 0; jj < 8; jj++) acc[jj] += f * (double)wr[jj][c];
  }
  if (!pv) return;
  #pragma unroll
  for (int jj = 0; jj < 8; jj++) {
    int oc = ocg * 8 + jj;
    if (oc >= 54) break;
    double v = acc[jj] + bias[jj];
    if (oc < 36) {
      locD[(size_t)n * 90000 + (size_t)p * 36 + oc] = v;
      out[(size_t)n * 90000 + (size_t)p * 36 + oc] = (float)v;
    } else {
      scoreD[(size_t)n * 45000 + (size_t)p * 18 + (oc - 36)] = v;
      out[360000 + (size_t)n * 45000 + (size_t)p * 18 + (oc - 36)] = (float)v;
    }
  }
}

// robust scalar decode: harness may deliver python ints as int32 or float32
__device__ inline double decode_dim(const int* p) {
  int v = p[0];
  if (v > 0 && v < 1000000) return (double)v;
  return (double)__int_as_float(v);
}

// ======================= anchors + loc2bbox + clip + valid + fg (f64) ========
__global__ void prep_kernel(const double* __restrict__ locD,
                            const double* __restrict__ scoreD,
                            const int* __restrict__ img_h_p, const int* __restrict__ img_w_p,
                            double* __restrict__ roiD, double* __restrict__ selD,
                            float* __restrict__ d_out)
{
  const int i = blockIdx.x * 256 + threadIdx.x;
  const int n = blockIdx.y;
  if (i >= 22500) return;
  const int p = i / 9, ab = i - p * 9;
  const int y = p / 50, x = p - y * 50;
  const int ri = ab / 3, sidx = ab - ri * 3;
  // base anchors: fp64 math, rounded ONCE to f32 (np.asarray(..,f32)); shift add in f32
  const double rr = (ri == 0) ? 0.5 : (ri == 1 ? 1.0 : 2.0);
  const double sc = (sidx == 0) ? 8.0 : (sidx == 1 ? 16.0 : 32.0);
  const double hh = 16.0 * sc * sqrt(rr);
  const double wd = 16.0 * sc * sqrt(1.0 / rr);
  const float bx1 = (float)(8.0 - wd * 0.5), by1 = (float)(8.0 - hh * 0.5);
  const float bx2 = (float)(8.0 + wd * 0.5), by2 = (float)(8.0 + hh * 0.5);
  const float sxf = (float)(x * 16), syf = (float)(y * 16);
  const float ax1 = bx1 + sxf, ay1 = by1 + syf, ax2 = bx2 + sxf, ay2 = by2 + syf;
  if (n == 0) {
    ((float4*)(d_out + 546000))[i] = make_float4(ax1, ay1, ax2, ay2);
  }
  const double l0 = locD[(size_t)n * 90000 + (size_t)i * 4 + 0];
  const double l1 = locD[(size_t)n * 90000 + (size_t)i * 4 + 1];
  const double l2 = locD[(size_t)n * 90000 + (size_t)i * 4 + 2];
  const double l3 = locD[(size_t)n * 90000 + (size_t)i * 4 + 3];
  const double s0 = scoreD[(size_t)n * 45000 + (size_t)i * 2 + 0];
  const double s1 = scoreD[(size_t)n * 45000 + (size_t)i * 2 + 1];
  const double aw = (double)ax2 - (double)ax1, ah = (double)ay2 - (double)ay1;
  const double acx = (double)ax1 + 0.5 * aw, acy = (double)ay1 + 0.5 * ah;
  const double cx = l0 * aw + acx, cy = l1 * ah + acy;
  const double ww = exp(l2) * aw, hh2 = exp(l3) * ah;
  double x1 = cx - 0.5 * ww, y1 = cy - 0.5 * hh2;
  double x2 = cx + 0.5 * ww, y2 = cy + 0.5 * hh2;
  const double fw = decode_dim(img_w_p), fh = decode_dim(img_h_p);
  x1 = fmin(fmax(x1, 0.0), fw); x2 = fmin(fmax(x2, 0.0), fw);
  y1 = fmin(fmax(y1, 0.0), fh); y2 = fmin(fmax(y2, 0.0), fh);
  const bool valid = (x2 - x1 + 1.0 >= 16.0) && (y2 - y1 + 1.0 >= 16.0);
  const double m = fmax(s0, s1);
  const double e0 = exp(s0 - m), e1 = exp(s1 - m);
  const double fg = e1 / (e0 + e1);
  double* rb = roiD + ((size_t)n * 22500 + i) * 4;
  rb[0] = x1; rb[1] = y1; rb[2] = x2; rb[3] = y2;
  selD[(size_t)n * 22500 + i] = valid ? fg : -INFINITY;
}

// ======================= exact rank (= lax.top_k order), f64 =================
__global__ __launch_bounds__(256) void rank_kernel(
    const double* __restrict__ selD, const double* __restrict__ roiD,
    double* __restrict__ sBoxD, int* __restrict__ sValid)
{
  const int n = blockIdx.y;
  const int i = blockIdx.x * 256 + threadIdx.x;
  const double* __restrict__ ss = selD + (size_t)n * 22500;
  const bool vi = (i < 22500);
  const int ii = vi ? i : 0;
  const double si = ss[ii];
  int rank = 0;
  #pragma unroll 4
  for (int j = 0; j < 22500; j++) {
    double sj = ss[j];
    rank += (sj > si) || (sj == si && j < ii);
  }
  if (vi && rank < 3000) {
    const double* rb = roiD + ((size_t)n * 22500 + ii) * 4;
    double* db = sBoxD + ((size_t)n * 3000 + rank) * 4;
    db[0] = rb[0]; db[1] = rb[1]; db[2] = rb[2]; db[3] = rb[3];
    sValid[(size_t)n * 3000 + rank] = (si > -INFINITY) ? 1 : 0;
  }
}

// ======================= fused greedy NMS + outputs (simple & transparent) ===
// one block per batch; alive bytes in LDS; sequential i, parallel j.
__global__ __launch_bounds__(512) void nms_kernel(
    const double* __restrict__ sBoxD, const int* __restrict__ sValid,
    float* __restrict__ out)
{
  const int n = blockIdx.x;
  const int tid = threadIdx.x;
  __shared__ unsigned char alive[3000];
  const double* __restrict__ B = sBoxD + (size_t)n * 3000 * 4;
  for (int j = tid; j < 3000; j += 512)
    alive[j] = (unsigned char)sValid[(size_t)n * 3000 + j];
  __syncthreads();
  for (int i = 0; i < 3000; i++) {
    if (alive[i]) {          // LDS broadcast -> uniform branch
      const double x1 = B[i * 4 + 0], y1 = B[i * 4 + 1];
      const double x2 = B[i * 4 + 2], y2 = B[i * 4 + 3];
      const double ai = (x2 - x1) * (y2 - y1);
      for (int j = i + 1 + tid; j < 3000; j += 512) {
        if (!alive[j]) continue;
        const double jx1 = B[j * 4 + 0], jy1 = B[j * 4 + 1];
        const double jx2 = B[j * 4 + 2], jy2 = B[j * 4 + 3];
        double iw = fmax(fmin(x2, jx2) - fmax(x1, jx1), 0.0);
        double ih = fmax(fmin(y2, jy2) - fmax(y1, jy1), 0.0);
        double inter = iw * ih;
        double aj = (jx2 - jx1) * (jy2 - jy1);
        double iou = inter / (ai + aj - inter + 1e-9);
        if (iou > 0.7) alive[j] = 0;
      }
    }
    __syncthreads();         // orders this iteration's kills before next read
  }
  if (tid == 0) {            // sequential extraction: kept (index==score order), pad 0
    float4* rois4 = (float4*)(out + 540000);
    int r = 0;
    for (int i = 0; i < 3000 && r < 300; i++) {
      if (alive[i]) {
        rois4[n * 300 + r] = make_float4((float)B[i * 4 + 0], (float)B[i * 4 + 1],
                                         (float)B[i * 4 + 2], (float)B[i * 4 + 3]);
        r++;
      }
    }
    for (; r < 300; r++) rois4[n * 300 + r] = make_float4(0, 0, 0, 0);
  }
  for (int k = tid; k < 300; k += 512)
    out[544800 + n * 300 + k] = (float)n;
}

// ======================= launch =======================
extern "C" void kernel_launch(void* const* d_in, const int* in_sizes, int n_in,
                              void* d_out, int out_size, void* d_ws, size_t ws_size,
                              hipStream_t stream) {
  const float* x        = (const float*)d_in[0];
  const float* conv1_w  = (const float*)d_in[1];
  const float* conv1_b  = (const float*)d_in[2];
  const float* loc_w    = (const float*)d_in[3];
  const float* loc_b    = (const float*)d_in[4];
  const float* score_w  = (const float*)d_in[5];
  const float* score_b  = (const float*)d_in[6];
  const int*   img_h    = (const int*)d_in[7];
  const int*   img_w    = (const int*)d_in[8];
  float* out = (float*)d_out;
  char* ws = (char*)d_ws;

  // live ranges: featD conv->heads only; then its region is recycled.
  double* featD  = (double*)(ws);                  // [0, 40,960,000)
  double* locD   = (double*)(ws + 40960000);       // [.., +2,880,000)
  double* scoreD = (double*)(ws + 43840000);       // [.., +1,440,000) ends 45,280,000
  // aliases into featD's dead region (all used strictly after heads_kernel):
  double* roiD   = (double*)(ws);                  // [0, 2,880,000)
  double* selD   = (double*)(ws + 2880000);        // [.., +720,000)
  double* sBoxD  = (double*)(ws + 3600000);        // [.., +384,000)
  int*    sValid = (int*)(ws + 4000000);           // [.., +48,000)

  conv3x3_kernel<<<dim3(25, 8, 4), 256, 0, stream>>>(x, conv1_w, conv1_b, featD);
  heads_kernel<<<dim3(10, 7, 4), 256, 0, stream>>>(featD, loc_w, loc_b, score_w, score_b,
                                                   locD, scoreD, out);
  prep_kernel<<<dim3(88, 4), 256, 0, stream>>>(locD, scoreD, img_h, img_w, roiD, selD, out);
  rank_kernel<<<dim3(88, 4), 256, 0, stream>>>(selD, roiD, sBoxD, sValid);
  nms_kernel<<<4, 512, 0, stream>>>(sBoxD, sValid, out);
}

// Round 5
// 4222.321 us; speedup vs baseline: 1.3072x; 1.3072x over previous
//
#include <hip/hip_runtime.h>
#include <hip/hip_bf16.h>
#include <math.h>

// ---------------- problem constants ----------------
// x: (4,512,50,50) f32; conv1_w: (512,512,3,3); heads: 36 loc + 18 score ch
// outputs (f32, concat): rpn_locs 360000 | rpn_scores 180000 @360000 |
//   rois 4800 @540000 | roi_indices 1200 @544800 | anchor 90000 @546000
//
// Numerics: proposal path in f64 end-to-end (harness ref is f64; R4 passed
// with absmax 1e-3 → selection decisions must be made in f64).
// R5: NMS -> parallel bitmask (supmat) + 1-wave register scan; rank -> chunked
// coalesced loads + wave-shfl broadcast. Conv untouched (R6 target).

#define CONV_ICH 8

// ======================= conv 3x3 + bias + relu (f64 accumulate) ============
__global__ __launch_bounds__(256) void conv3x3_kernel(
    const float* __restrict__ xg, const float* __restrict__ wg,
    const float* __restrict__ bg, double* __restrict__ featD)
{
  const int ygrp = blockIdx.x, ocb = blockIdx.y, n = blockIdx.z;
  const int t = threadIdx.x;
  const int tx = t & 15;      // x = tx*4 + xi
  const int toc = t >> 4;     // oc = oc0 + toc*4 + j
  const int y0 = ygrp * 2;
  const int oc0 = ocb * 64;

  __shared__ __align__(16) float sIn[CONV_ICH * 4 * 52];  // [ic][row(4)][52]
  __shared__ __align__(16) float sW[72 * 68];             // [ic*9+k][oc(64), pad 68]

  double acc[2][4][4];
  #pragma unroll
  for (int a = 0; a < 2; a++)
    #pragma unroll
    for (int b = 0; b < 4; b++)
      #pragma unroll
      for (int c = 0; c < 4; c++) acc[a][b][c] = 0.0;

  for (int chunk = 0; chunk < 512 / CONV_ICH; ++chunk) {
    const int ic0 = chunk * CONV_ICH;
    __syncthreads();
    for (int e = t; e < CONV_ICH * 4 * 52; e += 256) {
      int ic = e / 208;
      int rem = e - ic * 208;
      int r = rem / 52;
      int xx = rem - r * 52;
      int yy = y0 + r - 1;
      int xc = xx - 1;
      float v = 0.f;
      if (yy >= 0 && yy < 50 && xc >= 0 && xc < 50)
        v = xg[(((size_t)n * 512 + ic0 + ic) * 50 + yy) * 50 + xc];
      sIn[e] = v;
    }
    for (int e = t; e < 64 * CONV_ICH * 9; e += 256) {
      int oc = e / 72;
      int r = e - oc * 72;
      sW[r * 68 + oc] = wg[((size_t)(oc0 + oc) * 512 + ic0) * 9 + r];
    }
    __syncthreads();

    for (int icl = 0; icl < CONV_ICH; ++icl) {
      double rows[4][6];
      #pragma unroll
      for (int r = 0; r < 4; r++) {
        const float* pb = &sIn[icl * 208 + r * 52 + tx * 4];
        float4 a4 = *(const float4*)pb;
        float2 b2 = *(const float2*)(pb + 4);
        rows[r][0] = (double)a4.x; rows[r][1] = (double)a4.y;
        rows[r][2] = (double)a4.z; rows[r][3] = (double)a4.w;
        rows[r][4] = (double)b2.x; rows[r][5] = (double)b2.y;
      }
      #pragma unroll
      for (int k = 0; k < 9; k++) {
        const int ky = k / 3, kx = k - ky * 3;
        float4 wv = *(const float4*)&sW[(icl * 9 + k) * 68 + toc * 4];
        double wa[4] = {(double)wv.x, (double)wv.y, (double)wv.z, (double)wv.w};
        #pragma unroll
        for (int j = 0; j < 4; j++)
          #pragma unroll
          for (int yy = 0; yy < 2; yy++)
            #pragma unroll
            for (int xi = 0; xi < 4; xi++)
              acc[yy][j][xi] += wa[j] * rows[yy + ky][xi + kx];
      }
    }
  }
  #pragma unroll
  for (int j = 0; j < 4; j++) {
    const int oc = oc0 + toc * 4 + j;
    const double bias = (double)bg[oc];
    #pragma unroll
    for (int yy = 0; yy < 2; yy++) {
      const int y = y0 + yy;
      size_t rowbase = (((size_t)n * 512 + oc) * 50 + y) * 50;
      int xb = tx * 4;
      if (xb < 50) {
        int lim = (xb + 3 < 50) ? 4 : 2;   // xb==48 -> only 2 valid
        #pragma unroll
        for (int xi = 0; xi < 4; xi++) {
          if (xi < lim)
            featD[rowbase + xb + xi] = fmax(acc[yy][j][xi] + bias, 0.0);
        }
      }
    }
  }
}

// ======================= 1x1 heads (loc 36 + score 18), f64 =================
// p = PIXEL index in [0, 2500) per image (batch is blockIdx.z).
__global__ __launch_bounds__(256) void heads_kernel(
    const double* __restrict__ featD,
    const float* __restrict__ loc_w, const float* __restrict__ loc_b,
    const float* __restrict__ score_w, const float* __restrict__ score_b,
    double* __restrict__ locD, double* __restrict__ scoreD,
    float* __restrict__ out)
{
  const int p = blockIdx.x * 256 + threadIdx.x;
  const int ocg = blockIdx.y;
  const int n = blockIdx.z;
  const bool pv = (p < 2500);
  const int pp = pv ? p : 0;
  const double* fbase = featD + (size_t)n * 512 * 2500 + pp;

  const float* wr[8];
  double bias[8];
  #pragma unroll
  for (int jj = 0; jj < 8; jj++) {
    int oc = ocg * 8 + jj;
    int occ = (oc < 54) ? oc : 0;
    if (occ < 36) { wr[jj] = loc_w + (size_t)occ * 512; bias[jj] = (double)loc_b[occ]; }
    else { wr[jj] = score_w + (size_t)(occ - 36) * 512; bias[jj] = (double)score_b[occ - 36]; }
  }
  double acc[8] = {0, 0, 0, 0, 0, 0, 0, 0};
  for (int c = 0; c < 512; c++) {
    double f = fbase[(size_t)c * 2500];
    #pragma unroll
    for (int jj = 0; jj < 8; jj++) acc[jj] += f * (double)wr[jj][c];
  }
  if (!pv) return;
  #pragma unroll
  for (int jj = 0; jj < 8; jj++) {
    int oc = ocg * 8 + jj;
    if (oc >= 54) break;
    double v = acc[jj] + bias[jj];
    if (oc < 36) {
      locD[(size_t)n * 90000 + (size_t)p * 36 + oc] = v;
      out[(size_t)n * 90000 + (size_t)p * 36 + oc] = (float)v;
    } else {
      scoreD[(size_t)n * 45000 + (size_t)p * 18 + (oc - 36)] = v;
      out[360000 + (size_t)n * 45000 + (size_t)p * 18 + (oc - 36)] = (float)v;
    }
  }
}

// robust scalar decode: harness may deliver python ints as int32 or float32
__device__ inline double decode_dim(const int* p) {
  int v = p[0];
  if (v > 0 && v < 1000000) return (double)v;
  return (double)__int_as_float(v);
}

// ======================= anchors + loc2bbox + clip + valid + fg (f64) ========
__global__ void prep_kernel(const double* __restrict__ locD,
                            const double* __restrict__ scoreD,
                            const int* __restrict__ img_h_p, const int* __restrict__ img_w_p,
                            double* __restrict__ roiD, double* __restrict__ selD,
                            float* __restrict__ d_out)
{
  const int i = blockIdx.x * 256 + threadIdx.x;
  const int n = blockIdx.y;
  if (i >= 22500) return;
  const int p = i / 9, ab = i - p * 9;
  const int y = p / 50, x = p - y * 50;
  const int ri = ab / 3, sidx = ab - ri * 3;
  const double rr = (ri == 0) ? 0.5 : (ri == 1 ? 1.0 : 2.0);
  const double sc = (sidx == 0) ? 8.0 : (sidx == 1 ? 16.0 : 32.0);
  const double hh = 16.0 * sc * sqrt(rr);
  const double wd = 16.0 * sc * sqrt(1.0 / rr);
  const float bx1 = (float)(8.0 - wd * 0.5), by1 = (float)(8.0 - hh * 0.5);
  const float bx2 = (float)(8.0 + wd * 0.5), by2 = (float)(8.0 + hh * 0.5);
  const float sxf = (float)(x * 16), syf = (float)(y * 16);
  const float ax1 = bx1 + sxf, ay1 = by1 + syf, ax2 = bx2 + sxf, ay2 = by2 + syf;
  if (n == 0) {
    ((float4*)(d_out + 546000))[i] = make_float4(ax1, ay1, ax2, ay2);
  }
  const double l0 = locD[(size_t)n * 90000 + (size_t)i * 4 + 0];
  const double l1 = locD[(size_t)n * 90000 + (size_t)i * 4 + 1];
  const double l2 = locD[(size_t)n * 90000 + (size_t)i * 4 + 2];
  const double l3 = locD[(size_t)n * 90000 + (size_t)i * 4 + 3];
  const double s0 = scoreD[(size_t)n * 45000 + (size_t)i * 2 + 0];
  const double s1 = scoreD[(size_t)n * 45000 + (size_t)i * 2 + 1];
  const double aw = (double)ax2 - (double)ax1, ah = (double)ay2 - (double)ay1;
  const double acx = (double)ax1 + 0.5 * aw, acy = (double)ay1 + 0.5 * ah;
  const double cx = l0 * aw + acx, cy = l1 * ah + acy;
  const double ww = exp(l2) * aw, hh2 = exp(l3) * ah;
  double x1 = cx - 0.5 * ww, y1 = cy - 0.5 * hh2;
  double x2 = cx + 0.5 * ww, y2 = cy + 0.5 * hh2;
  const double fw = decode_dim(img_w_p), fh = decode_dim(img_h_p);
  x1 = fmin(fmax(x1, 0.0), fw); x2 = fmin(fmax(x2, 0.0), fw);
  y1 = fmin(fmax(y1, 0.0), fh); y2 = fmin(fmax(y2, 0.0), fh);
  const bool valid = (x2 - x1 + 1.0 >= 16.0) && (y2 - y1 + 1.0 >= 16.0);
  const double m = fmax(s0, s1);
  const double e0 = exp(s0 - m), e1 = exp(s1 - m);
  const double fg = e1 / (e0 + e1);
  double* rb = roiD + ((size_t)n * 22500 + i) * 4;
  rb[0] = x1; rb[1] = y1; rb[2] = x2; rb[3] = y2;
  selD[(size_t)n * 22500 + i] = valid ? fg : -INFINITY;
}

// ======================= exact rank (= lax.top_k order), f64 =================
// chunked: 64 coalesced loads per wave-chunk, then wave-shfl broadcast.
// rank = #{j : s_j > s_i or (s_j == s_i and j < i)}; pad scores -inf at
// j >= 22500 never count (ii < 22500 <= j fails the tie test).
__global__ __launch_bounds__(256) void rank_kernel(
    const double* __restrict__ selD, const double* __restrict__ roiD,
    double* __restrict__ sBoxD, int* __restrict__ sValid)
{
  const int n = blockIdx.y;
  const int i = blockIdx.x * 256 + threadIdx.x;
  const double* __restrict__ ss = selD + (size_t)n * 22500;
  const bool vi = (i < 22500);
  const int ii = vi ? i : 0;
  const double si = ss[ii];
  const int lane = threadIdx.x & 63;
  int rank = 0;
  for (int j0 = 0; j0 < 22500; j0 += 64) {
    const int jl = j0 + lane;
    const double v = (jl < 22500) ? ss[jl] : -INFINITY;
    #pragma unroll
    for (int t = 0; t < 64; t++) {
      const double sj = __shfl(v, t);
      const int j = j0 + t;
      rank += ((sj > si) || (sj == si && j < ii)) ? 1 : 0;
    }
  }
  if (vi && rank < 3000) {
    const double* rb = roiD + ((size_t)n * 22500 + ii) * 4;
    double* db = sBoxD + ((size_t)n * 3000 + rank) * 4;
    db[0] = rb[0]; db[1] = rb[1]; db[2] = rb[2]; db[3] = rb[3];
    sValid[(size_t)n * 3000 + rank] = (si > -INFINITY) ? 1 : 0;
  }
}

// ======================= NMS phase A: suppression bitmask (f64 IoU) ==========
// sup[n][i][wj] bit t: IoU(i, j=wj*64+t) > 0.7 && j > i  (mask-independent part)
__global__ void supmat_kernel(const double* __restrict__ sBoxD,
                              unsigned long long* __restrict__ sup)
{
  const int wj = blockIdx.x, ig = blockIdx.y, n = blockIdx.z;
  const int lane = threadIdx.x;
  const int i = ig * 64 + lane;
  __shared__ double jb[64][4];
  const int j0 = wj * 64;
  {
    int j = j0 + lane;
    if (j < 3000) {
      const double* b = sBoxD + ((size_t)n * 3000 + j) * 4;
      jb[lane][0] = b[0]; jb[lane][1] = b[1]; jb[lane][2] = b[2]; jb[lane][3] = b[3];
    } else {
      jb[lane][0] = 0; jb[lane][1] = 0; jb[lane][2] = 0; jb[lane][3] = 0;
    }
  }
  __syncthreads();
  if (i >= 3000) return;
  const double* bi = sBoxD + ((size_t)n * 3000 + i) * 4;
  const double bx1 = bi[0], by1 = bi[1], bx2 = bi[2], by2 = bi[3];
  const double ai = (bx2 - bx1) * (by2 - by1);
  unsigned long long m = 0;
  #pragma unroll 2
  for (int t = 0; t < 64; t++) {
    const int j = j0 + t;
    const double jx1 = jb[t][0], jy1 = jb[t][1], jx2 = jb[t][2], jy2 = jb[t][3];
    double iw = fmax(fmin(bx2, jx2) - fmax(bx1, jx1), 0.0);
    double ih = fmax(fmin(by2, jy2) - fmax(by1, jy1), 0.0);
    double inter = iw * ih;
    double aj = (jx2 - jx1) * (jy2 - jy1);
    double iou = inter / (ai + aj - inter + 1e-9);
    if (iou > 0.7 && j > i && j < 3000) m |= (1ull << t);
  }
  sup[((size_t)n * 3000 + i) * 47 + wj] = m;
}

// ======================= NMS phase B: scan + outputs =======================
// one wave per batch; lane l holds alive word l (bits l*64..l*64+63) in a reg.
__global__ void nms_scan_kernel(const double* __restrict__ sBoxD,
                                const int* __restrict__ sValid,
                                const unsigned long long* __restrict__ sup,
                                float* __restrict__ out)
{
  const int n = blockIdx.x;
  const int lane = threadIdx.x;
  unsigned long long alive = 0;
  for (int w = 0; w < 47; w++) {
    int idx = w * 64 + lane;
    int v = (idx < 3000) ? sValid[(size_t)n * 3000 + idx] : 0;
    unsigned long long bm = __ballot(v != 0);
    if (lane == w) alive = bm;
  }
  const unsigned long long* srow = sup + (size_t)n * 3000 * 47;
  unsigned long long next = (lane < 47) ? srow[lane] : 0ull;
  for (int i = 0; i < 3000; i++) {
    unsigned long long row = next;
    if (i + 1 < 3000) next = (lane < 47) ? srow[(size_t)(i + 1) * 47 + lane] : 0ull;
    unsigned long long aw = __shfl(alive, i >> 6);
    if ((aw >> (i & 63)) & 1ull) alive &= ~row;   // i alive -> kill its victims
  }
  // kept boxes in index order (== score order) -> first 300, zero-pad rest
  int c = __popcll(alive);
  int pre = c;
  #pragma unroll
  for (int off = 1; off < 64; off <<= 1) {
    int t2 = __shfl_up(pre, off);
    if (lane >= off) pre += t2;
  }
  const int excl = pre - c;
  const int tot = __shfl(pre, 63);
  float4* rois4 = (float4*)(out + 540000);
  unsigned long long a = alive;
  int r = excl;
  while (a) {
    int b = __ffsll((unsigned long long)a) - 1;
    a &= (a - 1);
    if (r < 300) {
      int i = lane * 64 + b;
      const double* bb = sBoxD + ((size_t)n * 3000 + i) * 4;
      rois4[n * 300 + r] = make_float4((float)bb[0], (float)bb[1],
                                       (float)bb[2], (float)bb[3]);
    }
    r++;
  }
  for (int k = tot + lane; k < 300; k += 64)
    rois4[n * 300 + k] = make_float4(0, 0, 0, 0);
  for (int k = lane; k < 300; k += 64)
    out[544800 + n * 300 + k] = (float)n;
}

// ======================= launch =======================
extern "C" void kernel_launch(void* const* d_in, const int* in_sizes, int n_in,
                              void* d_out, int out_size, void* d_ws, size_t ws_size,
                              hipStream_t stream) {
  const float* x        = (const float*)d_in[0];
  const float* conv1_w  = (const float*)d_in[1];
  const float* conv1_b  = (const float*)d_in[2];
  const float* loc_w    = (const float*)d_in[3];
  const float* loc_b    = (const float*)d_in[4];
  const float* score_w  = (const float*)d_in[5];
  const float* score_b  = (const float*)d_in[6];
  const int*   img_h    = (const int*)d_in[7];
  const int*   img_w    = (const int*)d_in[8];
  float* out = (float*)d_out;
  char* ws = (char*)d_ws;

  // live ranges: featD conv->heads only; then its region is recycled.
  double* featD  = (double*)(ws);                  // [0, 40,960,000)
  double* locD   = (double*)(ws + 40960000);       // [.., +2,880,000)
  double* scoreD = (double*)(ws + 43840000);       // [.., +1,440,000) ends 45,280,000
  // aliases into featD's dead region (all used strictly after heads_kernel):
  double* roiD   = (double*)(ws);                  // [0, 2,880,000)
  double* selD   = (double*)(ws + 2880000);        // [.., +720,000)
  double* sBoxD  = (double*)(ws + 3600000);        // [.., +384,000)
  int*    sValid = (int*)(ws + 4000000);           // [.., +48,000)
  unsigned long long* sup = (unsigned long long*)(ws + 4100000);  // +4,512,000 -> 8.6 MB

  conv3x3_kernel<<<dim3(25, 8, 4), 256, 0, stream>>>(x, conv1_w, conv1_b, featD);
  heads_kernel<<<dim3(10, 7, 4), 256, 0, stream>>>(featD, loc_w, loc_b, score_w, score_b,
                                                   locD, scoreD, out);
  prep_kernel<<<dim3(88, 4), 256, 0, stream>>>(locD, scoreD, img_h, img_w, roiD, selD, out);
  rank_kernel<<<dim3(88, 4), 256, 0, stream>>>(selD, roiD, sBoxD, sValid);
  supmat_kernel<<<dim3(47, 47, 4), 64, 0, stream>>>(sBoxD, sup);
  nms_scan_kernel<<<4, 64, 0, stream>>>(sBoxD, sValid, sup, out);
}

// Round 7
// 4158.142 us; speedup vs baseline: 1.3274x; 1.0154x over previous
//
#include <hip/hip_runtime.h>
#include <hip/hip_bf16.h>
#include <math.h>

// ---------------- problem constants ----------------
// x: (4,512,50,50) f32; conv1_w: (512,512,3,3); heads: 36 loc + 18 score ch
// outputs (f32, concat): rpn_locs 360000 | rpn_scores 180000 @360000 |
//   rois 4800 @540000 | roi_indices 1200 @544800 | anchor 90000 @546000
//
// Numerics: proposal path f64 end-to-end (ref=np is f64; R4/R5 passed 1e-3).
// R7: f64-MFMA conv kept, but the C/D fragment row mapping is now determined
// AT RUNTIME by a probe MFMA (D[m][n]=m pattern): M1 row=4*(lane>>4)+reg vs
// M2 row=(lane>>4)+4*reg. R6 assumed M1 blindly; outputs-0/1 thresholds are
// too loose to catch a channel permutation (lesson from R0's OOB episode).

typedef double f64x4 __attribute__((ext_vector_type(4)));

// ======================= conv 3x3 via f64 MFMA ==============================
// block 256 thr = 4 waves; tile 64 oc x 100 px (2 rows); grid (25,8,4).
// Per MFMA: A=W[16 oc][4 ic] (lane=16k+m), B=X[4 ic][16 px] (lane=16k+n).
__global__ __launch_bounds__(256) void conv3x3_kernel(
    const float* __restrict__ xg, const float* __restrict__ wg,
    const float* __restrict__ bg, double* __restrict__ featD)
{
  const int ygrp = blockIdx.x, ocb = blockIdx.y, n = blockIdx.z;
  const int t = threadIdx.x;
  const int lane = t & 63;
  const int wv = t >> 6;          // wave id 0..3 -> oc group
  const int lm = lane & 15;       // m (A) / n (B) within tile
  const int kq = lane >> 4;       // k 0..3
  const int y0 = ygrp * 2;
  const int oc0 = ocb * 64;

  // ---- C/D layout probe: A[m][k]=m, B[k][n]=(k==0) -> D[m][n]=m exactly ----
  bool isM2;
  {
    f64x4 pr = (f64x4){0., 0., 0., 0.};
    double pa = (double)lm;                  // A[m=lm][k=kq] = m
    double pb = (kq == 0) ? 1.0 : 0.0;       // B[k=kq][n=lm] = delta(k==0)
    pr = __builtin_amdgcn_mfma_f64_16x16x4f64(pa, pb, pr, 0, 0, 0);
    double v = __builtin_amdgcn_readfirstlane(pr[1]);  // lane0: M1->1, M2->4
    isM2 = (v > 2.5);
  }

  __shared__ double sIn[960];     // [ic:225][row(4):56][x:52] (+slack, zeroed)
  __shared__ double sW[2376];     // [(tap*4+ic):66][oc:64]

  // zero sIn once (incl. slack read by discarded pad lanes)
  for (int e = t; e < 960; e += 256) sIn[e] = 0.0;

  f64x4 acc[7];
  #pragma unroll
  for (int nt = 0; nt < 7; nt++) acc[nt] = (f64x4){0., 0., 0., 0.};

  int pbase[7];
  #pragma unroll
  for (int nt = 0; nt < 7; nt++) {
    int p = nt * 16 + lm;
    int py = p / 50, px = p - py * 50;     // pad px (p>=100): reads slack (0)
    pbase[nt] = kq * 225 + py * 56 + px;
  }

  for (int ic0 = 0; ic0 < 512; ic0 += 4) {
    __syncthreads();
    for (int e = t; e < 832; e += 256) {
      int ic = e / 208;
      int rem = e - ic * 208;
      int r = rem / 52;
      int xx = rem - r * 52;
      int yy = y0 + r - 1;
      int xc = xx - 1;
      float v = 0.f;
      if (yy >= 0 && yy < 50 && xc >= 0 && xc < 50)
        v = xg[(((size_t)n * 512 + ic0 + ic) * 50 + yy) * 50 + xc];
      sIn[ic * 225 + r * 56 + xx] = (double)v;
    }
    for (int e = t; e < 2304; e += 256) {
      int oc = e / 36;
      int rem = e - oc * 36;
      int ic = rem / 9;
      int tap = rem - ic * 9;
      sW[(tap * 4 + ic) * 66 + oc] =
          (double)wg[((size_t)(oc0 + oc) * 512 + ic0 + ic) * 9 + tap];
    }
    __syncthreads();

    #pragma unroll
    for (int tap = 0; tap < 9; tap++) {
      const int ky = tap / 3, kx = tap - ky * 3;
      const double a = sW[(tap * 4 + kq) * 66 + wv * 16 + lm];
      const int off = ky * 56 + kx;
      #pragma unroll
      for (int nt = 0; nt < 7; nt++) {
        const double b = sIn[pbase[nt] + off];
        acc[nt] = __builtin_amdgcn_mfma_f64_16x16x4f64(a, b, acc[nt], 0, 0, 0);
      }
    }
  }

  // epilogue: bias + relu (f64); row mapping per probe
  #pragma unroll
  for (int nt = 0; nt < 7; nt++) {
    int p = nt * 16 + lm;
    if (p < 100) {
      int py = p / 50, px = p - py * 50;
      int y = y0 + py;
      #pragma unroll
      for (int i = 0; i < 4; i++) {
        int row = isM2 ? (kq + 4 * i) : (kq * 4 + i);
        int oc = oc0 + wv * 16 + row;
        featD[(((size_t)n * 512 + oc) * 50 + y) * 50 + px] =
            fmax(acc[nt][i] + (double)bg[oc], 0.0);
      }
    }
  }
}

// ======================= 1x1 heads (loc 36 + score 18), f64 =================
// p = PIXEL index in [0, 2500) per image (batch is blockIdx.z).
__global__ __launch_bounds__(256) void heads_kernel(
    const double* __restrict__ featD,
    const float* __restrict__ loc_w, const float* __restrict__ loc_b,
    const float* __restrict__ score_w, const float* __restrict__ score_b,
    double* __restrict__ locD, double* __restrict__ scoreD,
    float* __restrict__ out)
{
  const int p = blockIdx.x * 256 + threadIdx.x;
  const int ocg = blockIdx.y;
  const int n = blockIdx.z;
  const bool pv = (p < 2500);
  const int pp = pv ? p : 0;
  const double* fbase = featD + (size_t)n * 512 * 2500 + pp;

  const float* wr[8];
  double bias[8];
  #pragma unroll
  for (int jj = 0; jj < 8; jj++) {
    int oc = ocg * 8 + jj;
    int occ = (oc < 54) ? oc : 0;
    if (occ < 36) { wr[jj] = loc_w + (size_t)occ * 512; bias[jj] = (double)loc_b[occ]; }
    else { wr[jj] = score_w + (size_t)(occ - 36) * 512; bias[jj] = (double)score_b[occ - 36]; }
  }
  double acc[8] = {0, 0, 0, 0, 0, 0, 0, 0};
  for (int c = 0; c < 512; c++) {
    double f = fbase[(size_t)c * 2500];
    #pragma unroll
    for (int jj = 0; jj < 8; jj++) acc[jj] += f * (double)wr[jj][c];
  }
  if (!pv) return;
  #pragma unroll
  for (int jj = 0; jj < 8; jj++) {
    int oc = ocg * 8 + jj;
    if (oc >= 54) break;
    double v = acc[jj] + bias[jj];
    if (oc < 36) {
      locD[(size_t)n * 90000 + (size_t)p * 36 + oc] = v;
      out[(size_t)n * 90000 + (size_t)p * 36 + oc] = (float)v;
    } else {
      scoreD[(size_t)n * 45000 + (size_t)p * 18 + (oc - 36)] = v;
      out[360000 + (size_t)n * 45000 + (size_t)p * 18 + (oc - 36)] = (float)v;
    }
  }
}

// robust scalar decode: harness may deliver python ints as int32 or float32
__device__ inline double decode_dim(const int* p) {
  int v = p[0];
  if (v > 0 && v < 1000000) return (double)v;
  return (double)__int_as_float(v);
}

// ======================= anchors + loc2bbox + clip + valid + fg (f64) ========
__global__ void prep_kernel(const double* __restrict__ locD,
                            const double* __restrict__ scoreD,
                            const int* __restrict__ img_h_p, const int* __restrict__ img_w_p,
                            double* __restrict__ roiD, double* __restrict__ selD,
                            float* __restrict__ d_out)
{
  const int i = blockIdx.x * 256 + threadIdx.x;
  const int n = blockIdx.y;
  if (i >= 22500) return;
  const int p = i / 9, ab = i - p * 9;
  const int y = p / 50, x = p - y * 50;
  const int ri = ab / 3, sidx = ab - ri * 3;
  const double rr = (ri == 0) ? 0.5 : (ri == 1 ? 1.0 : 2.0);
  const double sc = (sidx == 0) ? 8.0 : (sidx == 1 ? 16.0 : 32.0);
  const double hh = 16.0 * sc * sqrt(rr);
  const double wd = 16.0 * sc * sqrt(1.0 / rr);
  const float bx1 = (float)(8.0 - wd * 0.5), by1 = (float)(8.0 - hh * 0.5);
  const float bx2 = (float)(8.0 + wd * 0.5), by2 = (float)(8.0 + hh * 0.5);
  const float sxf = (float)(x * 16), syf = (float)(y * 16);
  const float ax1 = bx1 + sxf, ay1 = by1 + syf, ax2 = bx2 + sxf, ay2 = by2 + syf;
  if (n == 0) {
    ((float4*)(d_out + 546000))[i] = make_float4(ax1, ay1, ax2, ay2);
  }
  const double l0 = locD[(size_t)n * 90000 + (size_t)i * 4 + 0];
  const double l1 = locD[(size_t)n * 90000 + (size_t)i * 4 + 1];
  const double l2 = locD[(size_t)n * 90000 + (size_t)i * 4 + 2];
  const double l3 = locD[(size_t)n * 90000 + (size_t)i * 4 + 3];
  const double s0 = scoreD[(size_t)n * 45000 + (size_t)i * 2 + 0];
  const double s1 = scoreD[(size_t)n * 45000 + (size_t)i * 2 + 1];
  const double aw = (double)ax2 - (double)ax1, ah = (double)ay2 - (double)ay1;
  const double acx = (double)ax1 + 0.5 * aw, acy = (double)ay1 + 0.5 * ah;
  const double cx = l0 * aw + acx, cy = l1 * ah + acy;
  const double ww = exp(l2) * aw, hh2 = exp(l3) * ah;
  double x1 = cx - 0.5 * ww, y1 = cy - 0.5 * hh2;
  double x2 = cx + 0.5 * ww, y2 = cy + 0.5 * hh2;
  const double fw = decode_dim(img_w_p), fh = decode_dim(img_h_p);
  x1 = fmin(fmax(x1, 0.0), fw); x2 = fmin(fmax(x2, 0.0), fw);
  y1 = fmin(fmax(y1, 0.0), fh); y2 = fmin(fmax(y2, 0.0), fh);
  const bool valid = (x2 - x1 + 1.0 >= 16.0) && (y2 - y1 + 1.0 >= 16.0);
  const double m = fmax(s0, s1);
  const double e0 = exp(s0 - m), e1 = exp(s1 - m);
  const double fg = e1 / (e0 + e1);
  double* rb = roiD + ((size_t)n * 22500 + i) * 4;
  rb[0] = x1; rb[1] = y1; rb[2] = x2; rb[3] = y2;
  selD[(size_t)n * 22500 + i] = valid ? fg : -INFINITY;
}

// ======================= exact rank (= lax.top_k order), f64 =================
__global__ __launch_bounds__(256) void rank_kernel(
    const double* __restrict__ selD, const double* __restrict__ roiD,
    double* __restrict__ sBoxD, int* __restrict__ sValid)
{
  const int n = blockIdx.y;
  const int i = blockIdx.x * 256 + threadIdx.x;
  const double* __restrict__ ss = selD + (size_t)n * 22500;
  const bool vi = (i < 22500);
  const int ii = vi ? i : 0;
  const double si = ss[ii];
  const int lane = threadIdx.x & 63;
  int rank = 0;
  for (int j0 = 0; j0 < 22500; j0 += 64) {
    const int jl = j0 + lane;
    const double v = (jl < 22500) ? ss[jl] : -INFINITY;
    #pragma unroll
    for (int t = 0; t < 64; t++) {
      const double sj = __shfl(v, t);
      const int j = j0 + t;
      rank += ((sj > si) || (sj == si && j < ii)) ? 1 : 0;
    }
  }
  if (vi && rank < 3000) {
    const double* rb = roiD + ((size_t)n * 22500 + ii) * 4;
    double* db = sBoxD + ((size_t)n * 3000 + rank) * 4;
    db[0] = rb[0]; db[1] = rb[1]; db[2] = rb[2]; db[3] = rb[3];
    sValid[(size_t)n * 3000 + rank] = (si > -INFINITY) ? 1 : 0;
  }
}

// ======================= NMS phase A: suppression bitmask (f64 IoU) ==========
__global__ void supmat_kernel(const double* __restrict__ sBoxD,
                              unsigned long long* __restrict__ sup)
{
  const int wj = blockIdx.x, ig = blockIdx.y, n = blockIdx.z;
  const int lane = threadIdx.x;
  const int i = ig * 64 + lane;
  __shared__ double jb[64][4];
  const int j0 = wj * 64;
  {
    int j = j0 + lane;
    if (j < 3000) {
      const double* b = sBoxD + ((size_t)n * 3000 + j) * 4;
      jb[lane][0] = b[0]; jb[lane][1] = b[1]; jb[lane][2] = b[2]; jb[lane][3] = b[3];
    } else {
      jb[lane][0] = 0; jb[lane][1] = 0; jb[lane][2] = 0; jb[lane][3] = 0;
    }
  }
  __syncthreads();
  if (i >= 3000) return;
  const double* bi = sBoxD + ((size_t)n * 3000 + i) * 4;
  const double bx1 = bi[0], by1 = bi[1], bx2 = bi[2], by2 = bi[3];
  const double ai = (bx2 - bx1) * (by2 - by1);
  unsigned long long m = 0;
  #pragma unroll 2
  for (int t = 0; t < 64; t++) {
    const int j = j0 + t;
    const double jx1 = jb[t][0], jy1 = jb[t][1], jx2 = jb[t][2], jy2 = jb[t][3];
    double iw = fmax(fmin(bx2, jx2) - fmax(bx1, jx1), 0.0);
    double ih = fmax(fmin(by2, jy2) - fmax(by1, jy1), 0.0);
    double inter = iw * ih;
    double aj = (jx2 - jx1) * (jy2 - jy1);
    double iou = inter / (ai + aj - inter + 1e-9);
    if (iou > 0.7 && j > i && j < 3000) m |= (1ull << t);
  }
  sup[((size_t)n * 3000 + i) * 47 + wj] = m;
}

// ======================= NMS phase B: scan + outputs =======================
__global__ void nms_scan_kernel(const double* __restrict__ sBoxD,
                                const int* __restrict__ sValid,
                                const unsigned long long* __restrict__ sup,
                                float* __restrict__ out)
{
  const int n = blockIdx.x;
  const int lane = threadIdx.x;
  unsigned long long alive = 0;
  for (int w = 0; w < 47; w++) {
    int idx = w * 64 + lane;
    int v = (idx < 3000) ? sValid[(size_t)n * 3000 + idx] : 0;
    unsigned long long bm = __ballot(v != 0);
    if (lane == w) alive = bm;
  }
  const unsigned long long* srow = sup + (size_t)n * 3000 * 47;
  unsigned long long next = (lane < 47) ? srow[lane] : 0ull;
  for (int i = 0; i < 3000; i++) {
    unsigned long long row = next;
    if (i + 1 < 3000) next = (lane < 47) ? srow[(size_t)(i + 1) * 47 + lane] : 0ull;
    unsigned long long aw = __shfl(alive, i >> 6);
    if ((aw >> (i & 63)) & 1ull) alive &= ~row;
  }
  int c = __popcll(alive);
  int pre = c;
  #pragma unroll
  for (int off = 1; off < 64; off <<= 1) {
    int t2 = __shfl_up(pre, off);
    if (lane >= off) pre += t2;
  }
  const int excl = pre - c;
  const int tot = __shfl(pre, 63);
  float4* rois4 = (float4*)(out + 540000);
  unsigned long long a = alive;
  int r = excl;
  while (a) {
    int b = __ffsll((unsigned long long)a) - 1;
    a &= (a - 1);
    if (r < 300) {
      int i = lane * 64 + b;
      const double* bb = sBoxD + ((size_t)n * 3000 + i) * 4;
      rois4[n * 300 + r] = make_float4((float)bb[0], (float)bb[1],
                                       (float)bb[2], (float)bb[3]);
    }
    r++;
  }
  for (int k = tot + lane; k < 300; k += 64)
    rois4[n * 300 + k] = make_float4(0, 0, 0, 0);
  for (int k = lane; k < 300; k += 64)
    out[544800 + n * 300 + k] = (float)n;
}

// ======================= launch =======================
extern "C" void kernel_launch(void* const* d_in, const int* in_sizes, int n_in,
                              void* d_out, int out_size, void* d_ws, size_t ws_size,
                              hipStream_t stream) {
  const float* x        = (const float*)d_in[0];
  const float* conv1_w  = (const float*)d_in[1];
  const float* conv1_b  = (const float*)d_in[2];
  const float* loc_w    = (const float*)d_in[3];
  const float* loc_b    = (const float*)d_in[4];
  const float* score_w  = (const float*)d_in[5];
  const float* score_b  = (const float*)d_in[6];
  const int*   img_h    = (const int*)d_in[7];
  const int*   img_w    = (const int*)d_in[8];
  float* out = (float*)d_out;
  char* ws = (char*)d_ws;

  // live ranges: featD conv->heads only; then its region is recycled.
  double* featD  = (double*)(ws);                  // [0, 40,960,000)
  double* locD   = (double*)(ws + 40960000);       // [.., +2,880,000)
  double* scoreD = (double*)(ws + 43840000);       // [.., +1,440,000) ends 45,280,000
  // aliases into featD's dead region (all used strictly after heads_kernel):
  double* roiD   = (double*)(ws);                  // [0, 2,880,000)
  double* selD   = (double*)(ws + 2880000);        // [.., +720,000)
  double* sBoxD  = (double*)(ws + 3600000);        // [.., +384,000)
  int*    sValid = (int*)(ws + 4000000);           // [.., +48,000)
  unsigned long long* sup = (unsigned long long*)(ws + 4100000);  // +4,512,000

  conv3x3_kernel<<<dim3(25, 8, 4), 256, 0, stream>>>(x, conv1_w, conv1_b, featD);
  heads_kernel<<<dim3(10, 7, 4), 256, 0, stream>>>(featD, loc_w, loc_b, score_w, score_b,
                                                   locD, scoreD, out);
  prep_kernel<<<dim3(88, 4), 256, 0, stream>>>(locD, scoreD, img_h, img_w, roiD, selD, out);
  rank_kernel<<<dim3(88, 4), 256, 0, stream>>>(selD, roiD, sBoxD, sValid);
  supmat_kernel<<<dim3(47, 47, 4), 64, 0, stream>>>(sBoxD, sup);
  nms_scan_kernel<<<4, 64, 0, stream>>>(sBoxD, sValid, sup, out);
}

// Round 8
// 3596.338 us; speedup vs baseline: 1.5347x; 1.1562x over previous
//
#include <hip/hip_runtime.h>
#include <hip/hip_bf16.h>
#include <math.h>

// ---------------- problem constants ----------------
// x: (4,512,50,50) f32; conv1_w: (512,512,3,3); heads: 36 loc + 18 score ch
// outputs (f32, concat): rpn_locs 360000 | rpn_scores 180000 @360000 |
//   rois 4800 @540000 | roi_indices 1200 @544800 | anchor 90000 @546000
//
// Numerics: proposal path f64 end-to-end (ref=np is f64).
// R8: nms_scan gets a 12-deep register prefetch pipeline (was 1-deep: each of
// 3000 iters paid full memory latency serially -> ~1.4 ms); supmat skips
// below-diagonal blocks. Conv (runtime C/D-probe f64 MFMA, R7-passing) kept.

typedef double f64x4 __attribute__((ext_vector_type(4)));

// ======================= conv 3x3 via f64 MFMA ==============================
// block 256 thr = 4 waves; tile 64 oc x 100 px (2 rows); grid (25,8,4).
// Per MFMA: A=W[16 oc][4 ic] (lane=16k+m), B=X[4 ic][16 px] (lane=16k+n).
__global__ __launch_bounds__(256) void conv3x3_kernel(
    const float* __restrict__ xg, const float* __restrict__ wg,
    const float* __restrict__ bg, double* __restrict__ featD)
{
  const int ygrp = blockIdx.x, ocb = blockIdx.y, n = blockIdx.z;
  const int t = threadIdx.x;
  const int lane = t & 63;
  const int wv = t >> 6;          // wave id 0..3 -> oc group
  const int lm = lane & 15;       // m (A) / n (B) within tile
  const int kq = lane >> 4;       // k 0..3
  const int y0 = ygrp * 2;
  const int oc0 = ocb * 64;

  // ---- C/D layout probe: A[m][k]=m, B[k][n]=(k==0) -> D[m][n]=m exactly ----
  bool isM2;
  {
    f64x4 pr = (f64x4){0., 0., 0., 0.};
    double pa = (double)lm;                  // A[m=lm][k=kq] = m
    double pb = (kq == 0) ? 1.0 : 0.0;       // B[k=kq][n=lm] = delta(k==0)
    pr = __builtin_amdgcn_mfma_f64_16x16x4f64(pa, pb, pr, 0, 0, 0);
    double v = __builtin_amdgcn_readfirstlane(pr[1]);  // lane0: M1->1, M2->4
    isM2 = (v > 2.5);
  }

  __shared__ double sIn[960];     // [ic:225][row(4):56][x:52] (+slack, zeroed)
  __shared__ double sW[2376];     // [(tap*4+ic):66][oc:64]

  for (int e = t; e < 960; e += 256) sIn[e] = 0.0;

  f64x4 acc[7];
  #pragma unroll
  for (int nt = 0; nt < 7; nt++) acc[nt] = (f64x4){0., 0., 0., 0.};

  int pbase[7];
  #pragma unroll
  for (int nt = 0; nt < 7; nt++) {
    int p = nt * 16 + lm;
    int py = p / 50, px = p - py * 50;     // pad px (p>=100): reads slack (0)
    pbase[nt] = kq * 225 + py * 56 + px;
  }

  for (int ic0 = 0; ic0 < 512; ic0 += 4) {
    __syncthreads();
    for (int e = t; e < 832; e += 256) {
      int ic = e / 208;
      int rem = e - ic * 208;
      int r = rem / 52;
      int xx = rem - r * 52;
      int yy = y0 + r - 1;
      int xc = xx - 1;
      float v = 0.f;
      if (yy >= 0 && yy < 50 && xc >= 0 && xc < 50)
        v = xg[(((size_t)n * 512 + ic0 + ic) * 50 + yy) * 50 + xc];
      sIn[ic * 225 + r * 56 + xx] = (double)v;
    }
    for (int e = t; e < 2304; e += 256) {
      int oc = e / 36;
      int rem = e - oc * 36;
      int ic = rem / 9;
      int tap = rem - ic * 9;
      sW[(tap * 4 + ic) * 66 + oc] =
          (double)wg[((size_t)(oc0 + oc) * 512 + ic0 + ic) * 9 + tap];
    }
    __syncthreads();

    #pragma unroll
    for (int tap = 0; tap < 9; tap++) {
      const int ky = tap / 3, kx = tap - ky * 3;
      const double a = sW[(tap * 4 + kq) * 66 + wv * 16 + lm];
      const int off = ky * 56 + kx;
      #pragma unroll
      for (int nt = 0; nt < 7; nt++) {
        const double b = sIn[pbase[nt] + off];
        acc[nt] = __builtin_amdgcn_mfma_f64_16x16x4f64(a, b, acc[nt], 0, 0, 0);
      }
    }
  }

  #pragma unroll
  for (int nt = 0; nt < 7; nt++) {
    int p = nt * 16 + lm;
    if (p < 100) {
      int py = p / 50, px = p - py * 50;
      int y = y0 + py;
      #pragma unroll
      for (int i = 0; i < 4; i++) {
        int row = isM2 ? (kq + 4 * i) : (kq * 4 + i);
        int oc = oc0 + wv * 16 + row;
        featD[(((size_t)n * 512 + oc) * 50 + y) * 50 + px] =
            fmax(acc[nt][i] + (double)bg[oc], 0.0);
      }
    }
  }
}

// ======================= 1x1 heads (loc 36 + score 18), f64 =================
__global__ __launch_bounds__(256) void heads_kernel(
    const double* __restrict__ featD,
    const float* __restrict__ loc_w, const float* __restrict__ loc_b,
    const float* __restrict__ score_w, const float* __restrict__ score_b,
    double* __restrict__ locD, double* __restrict__ scoreD,
    float* __restrict__ out)
{
  const int p = blockIdx.x * 256 + threadIdx.x;
  const int ocg = blockIdx.y;
  const int n = blockIdx.z;
  const bool pv = (p < 2500);
  const int pp = pv ? p : 0;
  const double* fbase = featD + (size_t)n * 512 * 2500 + pp;

  const float* wr[8];
  double bias[8];
  #pragma unroll
  for (int jj = 0; jj < 8; jj++) {
    int oc = ocg * 8 + jj;
    int occ = (oc < 54) ? oc : 0;
    if (occ < 36) { wr[jj] = loc_w + (size_t)occ * 512; bias[jj] = (double)loc_b[occ]; }
    else { wr[jj] = score_w + (size_t)(occ - 36) * 512; bias[jj] = (double)score_b[occ - 36]; }
  }
  double acc[8] = {0, 0, 0, 0, 0, 0, 0, 0};
  for (int c = 0; c < 512; c++) {
    double f = fbase[(size_t)c * 2500];
    #pragma unroll
    for (int jj = 0; jj < 8; jj++) acc[jj] += f * (double)wr[jj][c];
  }
  if (!pv) return;
  #pragma unroll
  for (int jj = 0; jj < 8; jj++) {
    int oc = ocg * 8 + jj;
    if (oc >= 54) break;
    double v = acc[jj] + bias[jj];
    if (oc < 36) {
      locD[(size_t)n * 90000 + (size_t)p * 36 + oc] = v;
      out[(size_t)n * 90000 + (size_t)p * 36 + oc] = (float)v;
    } else {
      scoreD[(size_t)n * 45000 + (size_t)p * 18 + (oc - 36)] = v;
      out[360000 + (size_t)n * 45000 + (size_t)p * 18 + (oc - 36)] = (float)v;
    }
  }
}

// robust scalar decode: harness may deliver python ints as int32 or float32
__device__ inline double decode_dim(const int* p) {
  int v = p[0];
  if (v > 0 && v < 1000000) return (double)v;
  return (double)__int_as_float(v);
}

// ======================= anchors + loc2bbox + clip + valid + fg (f64) ========
__global__ void prep_kernel(const double* __restrict__ locD,
                            const double* __restrict__ scoreD,
                            const int* __restrict__ img_h_p, const int* __restrict__ img_w_p,
                            double* __restrict__ roiD, double* __restrict__ selD,
                            float* __restrict__ d_out)
{
  const int i = blockIdx.x * 256 + threadIdx.x;
  const int n = blockIdx.y;
  if (i >= 22500) return;
  const int p = i / 9, ab = i - p * 9;
  const int y = p / 50, x = p - y * 50;
  const int ri = ab / 3, sidx = ab - ri * 3;
  const double rr = (ri == 0) ? 0.5 : (ri == 1 ? 1.0 : 2.0);
  const double sc = (sidx == 0) ? 8.0 : (sidx == 1 ? 16.0 : 32.0);
  const double hh = 16.0 * sc * sqrt(rr);
  const double wd = 16.0 * sc * sqrt(1.0 / rr);
  const float bx1 = (float)(8.0 - wd * 0.5), by1 = (float)(8.0 - hh * 0.5);
  const float bx2 = (float)(8.0 + wd * 0.5), by2 = (float)(8.0 + hh * 0.5);
  const float sxf = (float)(x * 16), syf = (float)(y * 16);
  const float ax1 = bx1 + sxf, ay1 = by1 + syf, ax2 = bx2 + sxf, ay2 = by2 + syf;
  if (n == 0) {
    ((float4*)(d_out + 546000))[i] = make_float4(ax1, ay1, ax2, ay2);
  }
  const double l0 = locD[(size_t)n * 90000 + (size_t)i * 4 + 0];
  const double l1 = locD[(size_t)n * 90000 + (size_t)i * 4 + 1];
  const double l2 = locD[(size_t)n * 90000 + (size_t)i * 4 + 2];
  const double l3 = locD[(size_t)n * 90000 + (size_t)i * 4 + 3];
  const double s0 = scoreD[(size_t)n * 45000 + (size_t)i * 2 + 0];
  const double s1 = scoreD[(size_t)n * 45000 + (size_t)i * 2 + 1];
  const double aw = (double)ax2 - (double)ax1, ah = (double)ay2 - (double)ay1;
  const double acx = (double)ax1 + 0.5 * aw, acy = (double)ay1 + 0.5 * ah;
  const double cx = l0 * aw + acx, cy = l1 * ah + acy;
  const double ww = exp(l2) * aw, hh2 = exp(l3) * ah;
  double x1 = cx - 0.5 * ww, y1 = cy - 0.5 * hh2;
  double x2 = cx + 0.5 * ww, y2 = cy + 0.5 * hh2;
  const double fw = decode_dim(img_w_p), fh = decode_dim(img_h_p);
  x1 = fmin(fmax(x1, 0.0), fw); x2 = fmin(fmax(x2, 0.0), fw);
  y1 = fmin(fmax(y1, 0.0), fh); y2 = fmin(fmax(y2, 0.0), fh);
  const bool valid = (x2 - x1 + 1.0 >= 16.0) && (y2 - y1 + 1.0 >= 16.0);
  const double m = fmax(s0, s1);
  const double e0 = exp(s0 - m), e1 = exp(s1 - m);
  const double fg = e1 / (e0 + e1);
  double* rb = roiD + ((size_t)n * 22500 + i) * 4;
  rb[0] = x1; rb[1] = y1; rb[2] = x2; rb[3] = y2;
  selD[(size_t)n * 22500 + i] = valid ? fg : -INFINITY;
}

// ======================= exact rank (= lax.top_k order), f64 =================
__global__ __launch_bounds__(256) void rank_kernel(
    const double* __restrict__ selD, const double* __restrict__ roiD,
    double* __restrict__ sBoxD, int* __restrict__ sValid)
{
  const int n = blockIdx.y;
  const int i = blockIdx.x * 256 + threadIdx.x;
  const double* __restrict__ ss = selD + (size_t)n * 22500;
  const bool vi = (i < 22500);
  const int ii = vi ? i : 0;
  const double si = ss[ii];
  const int lane = threadIdx.x & 63;
  int rank = 0;
  for (int j0 = 0; j0 < 22500; j0 += 64) {
    const int jl = j0 + lane;
    const double v = (jl < 22500) ? ss[jl] : -INFINITY;
    #pragma unroll
    for (int t = 0; t < 64; t++) {
      const double sj = __shfl(v, t);
      const int j = j0 + t;
      rank += ((sj > si) || (sj == si && j < ii)) ? 1 : 0;
    }
  }
  if (vi && rank < 3000) {
    const double* rb = roiD + ((size_t)n * 22500 + ii) * 4;
    double* db = sBoxD + ((size_t)n * 3000 + rank) * 4;
    db[0] = rb[0]; db[1] = rb[1]; db[2] = rb[2]; db[3] = rb[3];
    sValid[(size_t)n * 3000 + rank] = (si > -INFINITY) ? 1 : 0;
  }
}

// ======================= NMS phase A: suppression bitmask (f64 IoU) ==========
// sup[n][i][wj] bit t: IoU(i, j=wj*64+t) > 0.7 && j > i
__global__ void supmat_kernel(const double* __restrict__ sBoxD,
                              unsigned long long* __restrict__ sup)
{
  const int wj = blockIdx.x, ig = blockIdx.y, n = blockIdx.z;
  const int lane = threadIdx.x;
  const int i = ig * 64 + lane;
  // below-diagonal block: every j in [wj*64, wj*64+63] < every i -> all zero
  if (wj < ig) {
    if (i < 3000) sup[((size_t)n * 3000 + i) * 47 + wj] = 0ull;
    return;
  }
  __shared__ double jb[64][4];
  const int j0 = wj * 64;
  {
    int j = j0 + lane;
    if (j < 3000) {
      const double* b = sBoxD + ((size_t)n * 3000 + j) * 4;
      jb[lane][0] = b[0]; jb[lane][1] = b[1]; jb[lane][2] = b[2]; jb[lane][3] = b[3];
    } else {
      jb[lane][0] = 0; jb[lane][1] = 0; jb[lane][2] = 0; jb[lane][3] = 0;
    }
  }
  __syncthreads();
  if (i >= 3000) return;
  const double* bi = sBoxD + ((size_t)n * 3000 + i) * 4;
  const double bx1 = bi[0], by1 = bi[1], bx2 = bi[2], by2 = bi[3];
  const double ai = (bx2 - bx1) * (by2 - by1);
  unsigned long long m = 0;
  #pragma unroll 2
  for (int t = 0; t < 64; t++) {
    const int j = j0 + t;
    const double jx1 = jb[t][0], jy1 = jb[t][1], jx2 = jb[t][2], jy2 = jb[t][3];
    double iw = fmax(fmin(bx2, jx2) - fmax(bx1, jx1), 0.0);
    double ih = fmax(fmin(by2, jy2) - fmax(by1, jy1), 0.0);
    double inter = iw * ih;
    double aj = (jx2 - jx1) * (jy2 - jy1);
    double iou = inter / (ai + aj - inter + 1e-9);
    if (iou > 0.7 && j > i && j < 3000) m |= (1ull << t);
  }
  sup[((size_t)n * 3000 + i) * 47 + wj] = m;
}

// ======================= NMS phase B: scan + outputs =======================
// one wave per batch; lane l holds alive word l; 12-deep load pipeline.
#define SCAN_DEPTH 12   // 3000 = 12 * 250
__global__ void nms_scan_kernel(const double* __restrict__ sBoxD,
                                const int* __restrict__ sValid,
                                const unsigned long long* __restrict__ sup,
                                float* __restrict__ out)
{
  const int n = blockIdx.x;
  const int lane = threadIdx.x;
  unsigned long long alive = 0;
  for (int w = 0; w < 47; w++) {
    int idx = w * 64 + lane;
    int v = (idx < 3000) ? sValid[(size_t)n * 3000 + idx] : 0;
    unsigned long long bm = __ballot(v != 0);
    if (lane == w) alive = bm;
  }
  const unsigned long long* srow = sup + (size_t)n * 3000 * 47;
  const bool ld = (lane < 47);
  unsigned long long buf[SCAN_DEPTH];
  #pragma unroll
  for (int d = 0; d < SCAN_DEPTH; d++)
    buf[d] = ld ? srow[(size_t)d * 47 + lane] : 0ull;
  for (int ib = 0; ib < 3000; ib += SCAN_DEPTH) {
    #pragma unroll
    for (int d = 0; d < SCAN_DEPTH; d++) {
      const int i = ib + d;
      const unsigned long long row = buf[d];          // issued DEPTH iters ago
      const int pf = i + SCAN_DEPTH;
      buf[d] = (ld && pf < 3000) ? srow[(size_t)pf * 47 + lane] : 0ull;
      const unsigned long long aw = __shfl(alive, i >> 6);
      if ((aw >> (i & 63)) & 1ull) alive &= ~row;
    }
  }
  // kept boxes in index order (== score order) -> first 300, zero-pad rest
  int c = __popcll(alive);
  int pre = c;
  #pragma unroll
  for (int off = 1; off < 64; off <<= 1) {
    int t2 = __shfl_up(pre, off);
    if (lane >= off) pre += t2;
  }
  const int excl = pre - c;
  const int tot = __shfl(pre, 63);
  float4* rois4 = (float4*)(out + 540000);
  unsigned long long a = alive;
  int r = excl;
  while (a) {
    int b = __ffsll((unsigned long long)a) - 1;
    a &= (a - 1);
    if (r < 300) {
      int i = lane * 64 + b;
      const double* bb = sBoxD + ((size_t)n * 3000 + i) * 4;
      rois4[n * 300 + r] = make_float4((float)bb[0], (float)bb[1],
                                       (float)bb[2], (float)bb[3]);
    }
    r++;
  }
  for (int k = tot + lane; k < 300; k += 64)
    rois4[n * 300 + k] = make_float4(0, 0, 0, 0);
  for (int k = lane; k < 300; k += 64)
    out[544800 + n * 300 + k] = (float)n;
}

// ======================= launch =======================
extern "C" void kernel_launch(void* const* d_in, const int* in_sizes, int n_in,
                              void* d_out, int out_size, void* d_ws, size_t ws_size,
                              hipStream_t stream) {
  const float* x        = (const float*)d_in[0];
  const float* conv1_w  = (const float*)d_in[1];
  const float* conv1_b  = (const float*)d_in[2];
  const float* loc_w    = (const float*)d_in[3];
  const float* loc_b    = (const float*)d_in[4];
  const float* score_w  = (const float*)d_in[5];
  const float* score_b  = (const float*)d_in[6];
  const int*   img_h    = (const int*)d_in[7];
  const int*   img_w    = (const int*)d_in[8];
  float* out = (float*)d_out;
  char* ws = (char*)d_ws;

  // live ranges: featD conv->heads only; then its region is recycled.
  double* featD  = (double*)(ws);                  // [0, 40,960,000)
  double* locD   = (double*)(ws + 40960000);       // [.., +2,880,000)
  double* scoreD = (double*)(ws + 43840000);       // [.., +1,440,000) ends 45,280,000
  // aliases into featD's dead region (all used strictly after heads_kernel):
  double* roiD   = (double*)(ws);                  // [0, 2,880,000)
  double* selD   = (double*)(ws + 2880000);        // [.., +720,000)
  double* sBoxD  = (double*)(ws + 3600000);        // [.., +384,000)
  int*    sValid = (int*)(ws + 4000000);           // [.., +48,000)
  unsigned long long* sup = (unsigned long long*)(ws + 4100000);  // +4,512,000

  conv3x3_kernel<<<dim3(25, 8, 4), 256, 0, stream>>>(x, conv1_w, conv1_b, featD);
  heads_kernel<<<dim3(10, 7, 4), 256, 0, stream>>>(featD, loc_w, loc_b, score_w, score_b,
                                                   locD, scoreD, out);
  prep_kernel<<<dim3(88, 4), 256, 0, stream>>>(locD, scoreD, img_h, img_w, roiD, selD, out);
  rank_kernel<<<dim3(88, 4), 256, 0, stream>>>(selD, roiD, sBoxD, sValid);
  supmat_kernel<<<dim3(47, 47, 4), 64, 0, stream>>>(sBoxD, sup);
  nms_scan_kernel<<<4, 64, 0, stream>>>(sBoxD, sValid, sup, out);
}

// Round 9
// 2627.030 us; speedup vs baseline: 2.1010x; 1.3690x over previous
//
#include <hip/hip_runtime.h>
#include <hip/hip_bf16.h>
#include <math.h>

// ---------------- problem constants ----------------
// x: (4,512,50,50) f32; conv1_w: (512,512,3,3); heads: 36 loc + 18 score ch
// outputs (f32, concat): rpn_locs 360000 | rpn_scores 180000 @360000 |
//   rois 4800 @540000 | roi_indices 1200 @544800 | anchor 90000 @546000
//
// Numerics: proposal path f64 end-to-end (ref=np is f64).
// R9: (1) conv double-buffered: global->reg loads overlap MFMAs, f32 LDS
// staging (cvt on read), 1 barrier/chunk. (2) rank via histogram threshold ->
// compact ~3-4k candidates -> exact O(M^2) rank (index tie-break preserved).

typedef double f64x4 __attribute__((ext_vector_type(4)));

// ======================= conv 3x3 via f64 MFMA, double-buffered =============
// block 256 thr = 4 waves; tile 64 oc x 100 px (2 rows); grid (25,8,4).
// Per MFMA: A=W[16 oc][4 ic] (lane=16k+m), B=X[4 ic][16 px] (lane=16k+n).
__global__ __launch_bounds__(256) void conv3x3_kernel(
    const float* __restrict__ xg, const float* __restrict__ wg,
    const float* __restrict__ bg, double* __restrict__ featD)
{
  const int ygrp = blockIdx.x, ocb = blockIdx.y, n = blockIdx.z;
  const int t = threadIdx.x;
  const int lane = t & 63;
  const int wv = t >> 6;          // wave id 0..3 -> oc group
  const int lm = lane & 15;       // m (A) / n (B) within tile
  const int kq = lane >> 4;       // k 0..3
  const int y0 = ygrp * 2;
  const int oc0 = ocb * 64;

  // ---- C/D layout probe: A[m][k]=m, B[k][n]=(k==0) -> D[m][n]=m exactly ----
  bool isM2;
  {
    f64x4 pr = (f64x4){0., 0., 0., 0.};
    double pa = (double)lm;
    double pb = (kq == 0) ? 1.0 : 0.0;
    pr = __builtin_amdgcn_mfma_f64_16x16x4f64(pa, pb, pr, 0, 0, 0);
    double v = __builtin_amdgcn_readfirstlane(pr[1]);  // lane0: M1->1, M2->4
    isM2 = (v > 2.5);
  }

  __shared__ float sIn[2][960];    // [ic:225][row(4):56][x:52] (+gaps zeroed)
  __shared__ float sW[2][2376];    // [(tap*4+ic):66][oc:64]

  // zero both buffers once (gaps stay zero; staged regions overwritten)
  for (int e = t; e < 1920; e += 256) { sIn[0][e % 960 + 0] = 0.f; }
  for (int e = t; e < 2 * 960; e += 256) ((float*)sIn)[e] = 0.f;
  __syncthreads();

  f64x4 acc[7];
  #pragma unroll
  for (int nt = 0; nt < 7; nt++) acc[nt] = (f64x4){0., 0., 0., 0.};

  int pbase[7];
  #pragma unroll
  for (int nt = 0; nt < 7; nt++) {
    int p = nt * 16 + lm;
    int py = p / 50, px = p - py * 50;   // pad lanes (p>=100) read junk, discarded
    pbase[nt] = kq * 225 + py * 56 + px;
  }

  float xr[4], wr9[9];
  // ---- load chunk 0 into registers ----
  #pragma unroll
  for (int k = 0; k < 4; k++) {
    int e = t + k * 256;
    float v = 0.f;
    if (e < 832) {
      int ic = e / 208, rem = e - ic * 208;
      int r = rem / 52, xx = rem - r * 52;
      int yy = y0 + r - 1, xc = xx - 1;
      if (yy >= 0 && yy < 50 && xc >= 0 && xc < 50)
        v = xg[(((size_t)n * 512 + ic) * 50 + yy) * 50 + xc];
    }
    xr[k] = v;
  }
  #pragma unroll
  for (int k = 0; k < 9; k++) {
    int e = t + k * 256;
    int oc = e / 36, rem = e - oc * 36;
    int ic = rem / 9, tap = rem - ic * 9;
    wr9[k] = wg[((size_t)(oc0 + oc) * 512 + ic) * 9 + tap];
  }
  // ---- store chunk 0 into buffer 0 ----
  #pragma unroll
  for (int k = 0; k < 4; k++) {
    int e = t + k * 256;
    if (e < 832) {
      int ic = e / 208, rem = e - ic * 208;
      int r = rem / 52, xx = rem - r * 52;
      sIn[0][ic * 225 + r * 56 + xx] = xr[k];
    }
  }
  #pragma unroll
  for (int k = 0; k < 9; k++) {
    int e = t + k * 256;
    int oc = e / 36, rem = e - oc * 36;
    int ic = rem / 9, tap = rem - ic * 9;
    sW[0][(tap * 4 + ic) * 66 + oc] = wr9[k];
  }

  for (int c = 0; c < 128; c++) {
    __syncthreads();                      // buf[c&1] ready for all waves
    const int cur = c & 1, nxt = cur ^ 1;
    const int ic0n = (c + 1) * 4;
    if (c + 1 < 128) {                    // issue global loads for chunk c+1
      #pragma unroll
      for (int k = 0; k < 4; k++) {
        int e = t + k * 256;
        float v = 0.f;
        if (e < 832) {
          int ic = e / 208, rem = e - ic * 208;
          int r = rem / 52, xx = rem - r * 52;
          int yy = y0 + r - 1, xc = xx - 1;
          if (yy >= 0 && yy < 50 && xc >= 0 && xc < 50)
            v = xg[(((size_t)n * 512 + ic0n + ic) * 50 + yy) * 50 + xc];
        }
        xr[k] = v;
      }
      #pragma unroll
      for (int k = 0; k < 9; k++) {
        int e = t + k * 256;
        int oc = e / 36, rem = e - oc * 36;
        int ic = rem / 9, tap = rem - ic * 9;
        wr9[k] = wg[((size_t)(oc0 + oc) * 512 + ic0n + ic) * 9 + tap];
      }
    }
    // ---- compute on buf[cur] (overlaps the loads above) ----
    #pragma unroll
    for (int tap = 0; tap < 9; tap++) {
      const int ky = tap / 3, kx = tap - ky * 3;
      const double a = (double)sW[cur][(tap * 4 + kq) * 66 + wv * 16 + lm];
      const int off = ky * 56 + kx;
      #pragma unroll
      for (int nt = 0; nt < 7; nt++) {
        const double b = (double)sIn[cur][pbase[nt] + off];
        acc[nt] = __builtin_amdgcn_mfma_f64_16x16x4f64(a, b, acc[nt], 0, 0, 0);
      }
    }
    // ---- store chunk c+1 into buf[nxt] ----
    if (c + 1 < 128) {
      #pragma unroll
      for (int k = 0; k < 4; k++) {
        int e = t + k * 256;
        if (e < 832) {
          int ic = e / 208, rem = e - ic * 208;
          int r = rem / 52, xx = rem - r * 52;
          sIn[nxt][ic * 225 + r * 56 + xx] = xr[k];
        }
      }
      #pragma unroll
      for (int k = 0; k < 9; k++) {
        int e = t + k * 256;
        int oc = e / 36, rem = e - oc * 36;
        int ic = rem / 9, tap = rem - ic * 9;
        sW[nxt][(tap * 4 + ic) * 66 + oc] = wr9[k];
      }
    }
  }

  // epilogue: bias + relu (f64); row mapping per probe
  #pragma unroll
  for (int nt = 0; nt < 7; nt++) {
    int p = nt * 16 + lm;
    if (p < 100) {
      int py = p / 50, px = p - py * 50;
      int y = y0 + py;
      #pragma unroll
      for (int i = 0; i < 4; i++) {
        int row = isM2 ? (kq + 4 * i) : (kq * 4 + i);
        int oc = oc0 + wv * 16 + row;
        featD[(((size_t)n * 512 + oc) * 50 + y) * 50 + px] =
            fmax(acc[nt][i] + (double)bg[oc], 0.0);
      }
    }
  }
}

// ======================= 1x1 heads (loc 36 + score 18), f64 =================
__global__ __launch_bounds__(256) void heads_kernel(
    const double* __restrict__ featD,
    const float* __restrict__ loc_w, const float* __restrict__ loc_b,
    const float* __restrict__ score_w, const float* __restrict__ score_b,
    double* __restrict__ locD, double* __restrict__ scoreD,
    float* __restrict__ out)
{
  const int p = blockIdx.x * 256 + threadIdx.x;
  const int ocg = blockIdx.y;
  const int n = blockIdx.z;
  const bool pv = (p < 2500);
  const int pp = pv ? p : 0;
  const double* fbase = featD + (size_t)n * 512 * 2500 + pp;

  const float* wr[8];
  double bias[8];
  #pragma unroll
  for (int jj = 0; jj < 8; jj++) {
    int oc = ocg * 8 + jj;
    int occ = (oc < 54) ? oc : 0;
    if (occ < 36) { wr[jj] = loc_w + (size_t)occ * 512; bias[jj] = (double)loc_b[occ]; }
    else { wr[jj] = score_w + (size_t)(occ - 36) * 512; bias[jj] = (double)score_b[occ - 36]; }
  }
  double acc[8] = {0, 0, 0, 0, 0, 0, 0, 0};
  for (int c = 0; c < 512; c++) {
    double f = fbase[(size_t)c * 2500];
    #pragma unroll
    for (int jj = 0; jj < 8; jj++) acc[jj] += f * (double)wr[jj][c];
  }
  if (!pv) return;
  #pragma unroll
  for (int jj = 0; jj < 8; jj++) {
    int oc = ocg * 8 + jj;
    if (oc >= 54) break;
    double v = acc[jj] + bias[jj];
    if (oc < 36) {
      locD[(size_t)n * 90000 + (size_t)p * 36 + oc] = v;
      out[(size_t)n * 90000 + (size_t)p * 36 + oc] = (float)v;
    } else {
      scoreD[(size_t)n * 45000 + (size_t)p * 18 + (oc - 36)] = v;
      out[360000 + (size_t)n * 45000 + (size_t)p * 18 + (oc - 36)] = (float)v;
    }
  }
}

// robust scalar decode: harness may deliver python ints as int32 or float32
__device__ inline double decode_dim(const int* p) {
  int v = p[0];
  if (v > 0 && v < 1000000) return (double)v;
  return (double)__int_as_float(v);
}

// ======================= zero ws counters (after heads; aliases featD) =======
__global__ void zero_kernel(unsigned* __restrict__ hist, int* __restrict__ sValid,
                            unsigned* __restrict__ cnt)
{
  const int i = blockIdx.x * 256 + threadIdx.x;
  if (i < 262144) hist[i] = 0u;
  if (i < 12000) sValid[i] = 0;
  if (i < 4) cnt[i] = 0u;
}

// ======================= anchors + loc2bbox + clip + valid + fg (f64) ========
__global__ void prep_kernel(const double* __restrict__ locD,
                            const double* __restrict__ scoreD,
                            const int* __restrict__ img_h_p, const int* __restrict__ img_w_p,
                            double* __restrict__ roiD, double* __restrict__ selD,
                            unsigned* __restrict__ hist, float* __restrict__ d_out)
{
  const int i = blockIdx.x * 256 + threadIdx.x;
  const int n = blockIdx.y;
  if (i >= 22500) return;
  const int p = i / 9, ab = i - p * 9;
  const int y = p / 50, x = p - y * 50;
  const int ri = ab / 3, sidx = ab - ri * 3;
  const double rr = (ri == 0) ? 0.5 : (ri == 1 ? 1.0 : 2.0);
  const double sc = (sidx == 0) ? 8.0 : (sidx == 1 ? 16.0 : 32.0);
  const double hh = 16.0 * sc * sqrt(rr);
  const double wd = 16.0 * sc * sqrt(1.0 / rr);
  const float bx1 = (float)(8.0 - wd * 0.5), by1 = (float)(8.0 - hh * 0.5);
  const float bx2 = (float)(8.0 + wd * 0.5), by2 = (float)(8.0 + hh * 0.5);
  const float sxf = (float)(x * 16), syf = (float)(y * 16);
  const float ax1 = bx1 + sxf, ay1 = by1 + syf, ax2 = bx2 + sxf, ay2 = by2 + syf;
  if (n == 0) {
    ((float4*)(d_out + 546000))[i] = make_float4(ax1, ay1, ax2, ay2);
  }
  const double l0 = locD[(size_t)n * 90000 + (size_t)i * 4 + 0];
  const double l1 = locD[(size_t)n * 90000 + (size_t)i * 4 + 1];
  const double l2 = locD[(size_t)n * 90000 + (size_t)i * 4 + 2];
  const double l3 = locD[(size_t)n * 90000 + (size_t)i * 4 + 3];
  const double s0 = scoreD[(size_t)n * 45000 + (size_t)i * 2 + 0];
  const double s1 = scoreD[(size_t)n * 45000 + (size_t)i * 2 + 1];
  const double aw = (double)ax2 - (double)ax1, ah = (double)ay2 - (double)ay1;
  const double acx = (double)ax1 + 0.5 * aw, acy = (double)ay1 + 0.5 * ah;
  const double cx = l0 * aw + acx, cy = l1 * ah + acy;
  const double ww = exp(l2) * aw, hh2 = exp(l3) * ah;
  double x1 = cx - 0.5 * ww, y1 = cy - 0.5 * hh2;
  double x2 = cx + 0.5 * ww, y2 = cy + 0.5 * hh2;
  const double fw = decode_dim(img_w_p), fh = decode_dim(img_h_p);
  x1 = fmin(fmax(x1, 0.0), fw); x2 = fmin(fmax(x2, 0.0), fw);
  y1 = fmin(fmax(y1, 0.0), fh); y2 = fmin(fmax(y2, 0.0), fh);
  const bool valid = (x2 - x1 + 1.0 >= 16.0) && (y2 - y1 + 1.0 >= 16.0);
  const double m = fmax(s0, s1);
  const double e0 = exp(s0 - m), e1 = exp(s1 - m);
  const double fg = e1 / (e0 + e1);
  double* rb = roiD + ((size_t)n * 22500 + i) * 4;
  rb[0] = x1; rb[1] = y1; rb[2] = x2; rb[3] = y2;
  selD[(size_t)n * 22500 + i] = valid ? fg : -INFINITY;
  if (valid) {  // fg in (0,1): positive f64 -> bits order == value order
    unsigned key = (unsigned)((unsigned long long)__double_as_longlong(fg) >> 48);
    atomicAdd(&hist[n * 65536 + key], 1u);
  }
}

// ======================= threshold: largest key class covering top-3000 ======
__global__ __launch_bounds__(256) void thresh_kernel(
    const unsigned* __restrict__ hist, unsigned* __restrict__ thrP)
{
  const int n = blockIdx.x;
  const int t = threadIdx.x;
  __shared__ unsigned csum[256];
  const unsigned* h = hist + (size_t)n * 65536;
  unsigned s = 0;
  for (int k = 0; k < 256; k++) s += h[t * 256 + k];
  csum[t] = s;
  __syncthreads();
  if (t == 0) {
    unsigned suf = 0, Tkey = 0;
    for (int c = 255; c >= 0; c--) {
      if (suf + csum[c] >= 3000u) {
        for (int v = c * 256 + 255; v >= c * 256; v--) {
          suf += h[v];
          if (suf >= 3000u) { Tkey = (unsigned)v; break; }
        }
        break;
      }
      suf += csum[c];
    }
    thrP[n] = Tkey;   // 0 if <3000 valid -> all valid become candidates
  }
}

// ======================= compact candidates (key >= threshold) ===============
__global__ void compact_kernel(const double* __restrict__ selD,
                               const unsigned* __restrict__ thrP,
                               unsigned* __restrict__ cnt,
                               int* __restrict__ candIdx, double* __restrict__ candS)
{
  const int i = blockIdx.x * 256 + threadIdx.x;
  const int n = blockIdx.y;
  if (i >= 22500) return;
  const double s = selD[(size_t)n * 22500 + i];
  if (!(s > -INFINITY)) return;
  unsigned key = (unsigned)((unsigned long long)__double_as_longlong(s) >> 48);
  if (key < thrP[n]) return;
  unsigned pos = atomicAdd(&cnt[n], 1u);
  candIdx[(size_t)n * 22500 + pos] = i;
  candS[(size_t)n * 22500 + pos] = s;
}

// ======================= exact rank among candidates (= lax.top_k order) =====
// global rank of any top-3000 element is fully determined within the
// candidate set (scores below the threshold class cannot outrank them).
__global__ __launch_bounds__(256) void crank_kernel(
    const unsigned* __restrict__ cnt, const int* __restrict__ candIdx,
    const double* __restrict__ candS, const double* __restrict__ roiD,
    double* __restrict__ sBoxD, int* __restrict__ sValid)
{
  const int n = blockIdx.y;
  const int m = (int)cnt[n];
  if ((int)(blockIdx.x * 256) >= m) return;   // block-uniform early exit
  const int tid = blockIdx.x * 256 + threadIdx.x;
  const bool act = (tid < m);
  const double si = act ? candS[(size_t)n * 22500 + tid] : 0.0;
  const int ii = act ? candIdx[(size_t)n * 22500 + tid] : 0x7fffffff;
  __shared__ double sv[256];
  __shared__ int siv[256];
  int rank = 0;
  for (int j0 = 0; j0 < m; j0 += 256) {
    __syncthreads();
    const int jl = j0 + threadIdx.x;
    if (jl < m) {
      sv[threadIdx.x] = candS[(size_t)n * 22500 + jl];
      siv[threadIdx.x] = candIdx[(size_t)n * 22500 + jl];
    }
    __syncthreads();
    const int lim = (m - j0 < 256) ? (m - j0) : 256;
    for (int k = 0; k < lim; k++) {
      const double sj = sv[k];
      const int ij = siv[k];
      rank += ((sj > si) || (sj == si && ij < ii)) ? 1 : 0;
    }
  }
  if (act && rank < 3000) {
    const double* rb = roiD + ((size_t)n * 22500 + ii) * 4;
    double* db = sBoxD + ((size_t)n * 3000 + rank) * 4;
    db[0] = rb[0]; db[1] = rb[1]; db[2] = rb[2]; db[3] = rb[3];
    sValid[n * 3000 + rank] = 1;
  }
}

// ======================= NMS phase A: suppression bitmask (f64 IoU) ==========
__global__ void supmat_kernel(const double* __restrict__ sBoxD,
                              unsigned long long* __restrict__ sup)
{
  const int wj = blockIdx.x, ig = blockIdx.y, n = blockIdx.z;
  const int lane = threadIdx.x;
  const int i = ig * 64 + lane;
  if (wj < ig) {                       // strictly below diagonal: all zero
    if (i < 3000) sup[((size_t)n * 3000 + i) * 47 + wj] = 0ull;
    return;
  }
  __shared__ double jb[64][4];
  const int j0 = wj * 64;
  {
    int j = j0 + lane;
    if (j < 3000) {
      const double* b = sBoxD + ((size_t)n * 3000 + j) * 4;
      jb[lane][0] = b[0]; jb[lane][1] = b[1]; jb[lane][2] = b[2]; jb[lane][3] = b[3];
    } else {
      jb[lane][0] = 0; jb[lane][1] = 0; jb[lane][2] = 0; jb[lane][3] = 0;
    }
  }
  __syncthreads();
  if (i >= 3000) return;
  const double* bi = sBoxD + ((size_t)n * 3000 + i) * 4;
  const double bx1 = bi[0], by1 = bi[1], bx2 = bi[2], by2 = bi[3];
  const double ai = (bx2 - bx1) * (by2 - by1);
  unsigned long long msk = 0;
  #pragma unroll 2
  for (int tt = 0; tt < 64; tt++) {
    const int j = j0 + tt;
    const double jx1 = jb[tt][0], jy1 = jb[tt][1], jx2 = jb[tt][2], jy2 = jb[tt][3];
    double iw = fmax(fmin(bx2, jx2) - fmax(bx1, jx1), 0.0);
    double ih = fmax(fmin(by2, jy2) - fmax(by1, jy1), 0.0);
    double inter = iw * ih;
    double aj = (jx2 - jx1) * (jy2 - jy1);
    double iou = inter / (ai + aj - inter + 1e-9);
    if (iou > 0.7 && j > i && j < 3000) msk |= (1ull << tt);
  }
  sup[((size_t)n * 3000 + i) * 47 + wj] = msk;
}

// ======================= NMS phase B: scan + outputs =======================
#define SCAN_DEPTH 12   // 3000 = 12 * 250
__global__ void nms_scan_kernel(const double* __restrict__ sBoxD,
                                const int* __restrict__ sValid,
                                const unsigned long long* __restrict__ sup,
                                float* __restrict__ out)
{
  const int n = blockIdx.x;
  const int lane = threadIdx.x;
  unsigned long long alive = 0;
  for (int w = 0; w < 47; w++) {
    int idx = w * 64 + lane;
    int v = (idx < 3000) ? sValid[(size_t)n * 3000 + idx] : 0;
    unsigned long long bm = __ballot(v != 0);
    if (lane == w) alive = bm;
  }
  const unsigned long long* srow = sup + (size_t)n * 3000 * 47;
  const bool ld = (lane < 47);
  unsigned long long buf[SCAN_DEPTH];
  #pragma unroll
  for (int d = 0; d < SCAN_DEPTH; d++)
    buf[d] = ld ? srow[(size_t)d * 47 + lane] : 0ull;
  for (int ib = 0; ib < 3000; ib += SCAN_DEPTH) {
    #pragma unroll
    for (int d = 0; d < SCAN_DEPTH; d++) {
      const int i = ib + d;
      const unsigned long long row = buf[d];
      const int pf = i + SCAN_DEPTH;
      buf[d] = (ld && pf < 3000) ? srow[(size_t)pf * 47 + lane] : 0ull;
      const unsigned long long aw = __shfl(alive, i >> 6);
      if ((aw >> (i & 63)) & 1ull) alive &= ~row;
    }
  }
  int c = __popcll(alive);
  int pre = c;
  #pragma unroll
  for (int off = 1; off < 64; off <<= 1) {
    int t2 = __shfl_up(pre, off);
    if (lane >= off) pre += t2;
  }
  const int excl = pre - c;
  const int tot = __shfl(pre, 63);
  float4* rois4 = (float4*)(out + 540000);
  unsigned long long a = alive;
  int r = excl;
  while (a) {
    int b = __ffsll((unsigned long long)a) - 1;
    a &= (a - 1);
    if (r < 300) {
      int i = lane * 64 + b;
      const double* bb = sBoxD + ((size_t)n * 3000 + i) * 4;
      rois4[n * 300 + r] = make_float4((float)bb[0], (float)bb[1],
                                       (float)bb[2], (float)bb[3]);
    }
    r++;
  }
  for (int k = tot + lane; k < 300; k += 64)
    rois4[n * 300 + k] = make_float4(0, 0, 0, 0);
  for (int k = lane; k < 300; k += 64)
    out[544800 + n * 300 + k] = (float)n;
}

// ======================= launch =======================
extern "C" void kernel_launch(void* const* d_in, const int* in_sizes, int n_in,
                              void* d_out, int out_size, void* d_ws, size_t ws_size,
                              hipStream_t stream) {
  const float* x        = (const float*)d_in[0];
  const float* conv1_w  = (const float*)d_in[1];
  const float* conv1_b  = (const float*)d_in[2];
  const float* loc_w    = (const float*)d_in[3];
  const float* loc_b    = (const float*)d_in[4];
  const float* score_w  = (const float*)d_in[5];
  const float* score_b  = (const float*)d_in[6];
  const int*   img_h    = (const int*)d_in[7];
  const int*   img_w    = (const int*)d_in[8];
  float* out = (float*)d_out;
  char* ws = (char*)d_ws;

  // live ranges: featD conv->heads only; then its region is recycled.
  double* featD  = (double*)(ws);                  // [0, 40,960,000)
  double* locD   = (double*)(ws + 40960000);       // +2,880,000
  double* scoreD = (double*)(ws + 43840000);       // +1,440,000 -> 45,280,000
  // aliases into featD's dead region (all used strictly after heads_kernel):
  double* roiD   = (double*)(ws);                  // [0, 2,880,000)
  double* selD   = (double*)(ws + 2880000);        // +720,000
  double* sBoxD  = (double*)(ws + 3600000);        // +384,000
  int*    sValid = (int*)(ws + 4000000);           // +48,000
  unsigned long long* sup = (unsigned long long*)(ws + 4100000);  // +4,512,000
  unsigned* hist   = (unsigned*)(ws + 8700000);    // +1,048,576
  unsigned* cnt    = (unsigned*)(ws + 9750000);    // +16
  unsigned* thrP   = (unsigned*)(ws + 9751040);    // +16
  int*      candIdx= (int*)(ws + 9752000);         // +360,000
  double*   candS  = (double*)(ws + 10200000);     // +720,000 -> 10,920,000

  conv3x3_kernel<<<dim3(25, 8, 4), 256, 0, stream>>>(x, conv1_w, conv1_b, featD);
  heads_kernel<<<dim3(10, 7, 4), 256, 0, stream>>>(featD, loc_w, loc_b, score_w, score_b,
                                                   locD, scoreD, out);
  zero_kernel<<<1024, 256, 0, stream>>>(hist, sValid, cnt);
  prep_kernel<<<dim3(88, 4), 256, 0, stream>>>(locD, scoreD, img_h, img_w,
                                               roiD, selD, hist, out);
  thresh_kernel<<<4, 256, 0, stream>>>(hist, thrP);
  compact_kernel<<<dim3(88, 4), 256, 0, stream>>>(selD, thrP, cnt, candIdx, candS);
  crank_kernel<<<dim3(88, 4), 256, 0, stream>>>(cnt, candIdx, candS, roiD, sBoxD, sValid);
  supmat_kernel<<<dim3(47, 47, 4), 64, 0, stream>>>(sBoxD, sup);
  nms_scan_kernel<<<4, 64, 0, stream>>>(sBoxD, sValid, sup, out);
}

// Round 10
// 2499.801 us; speedup vs baseline: 2.2079x; 1.0509x over previous
//
#include <hip/hip_runtime.h>
#include <hip/hip_bf16.h>
#include <math.h>

// ---------------- problem constants ----------------
// x: (4,512,50,50) f32; conv1_w: (512,512,3,3); heads: 36 loc + 18 score ch
// outputs (f32, concat): rpn_locs 360000 | rpn_scores 180000 @360000 |
//   rois 4800 @540000 | roi_indices 1200 @544800 | anchor 90000 @546000
//
// Numerics: proposal path f64 end-to-end (ref=np is f64).
// R10: conv regridded to 1 row/block (1600 blocks -> 6.25 waves/SIMD, was
// 3.125: grid was the occupancy limit at MfmaUtil 52%); LDS strides tuned to
// 2-way bank aliasing (free). heads: weights staged in LDS (broadcast reads).

typedef double f64x4 __attribute__((ext_vector_type(4)));

// ======================= conv 3x3 via f64 MFMA, double-buffered =============
// block 256 thr = 4 waves; tile 64 oc x 50 px (1 row); grid (50,8,4).
// Per MFMA: A=W[16 oc][4 ic] (lane=16k+m), B=X[4 ic][16 px] (lane=16k+n).
__global__ __launch_bounds__(256) void conv3x3_kernel(
    const float* __restrict__ xg, const float* __restrict__ wg,
    const float* __restrict__ bg, double* __restrict__ featD)
{
  const int y0 = blockIdx.x, ocb = blockIdx.y, n = blockIdx.z;
  const int t = threadIdx.x;
  const int lane = t & 63;
  const int wv = t >> 6;          // wave id 0..3 -> oc group
  const int lm = lane & 15;       // m (A) / n (B) within tile
  const int kq = lane >> 4;       // k 0..3
  const int oc0 = ocb * 64;

  // ---- C/D layout probe: A[m][k]=m, B[k][n]=(k==0) -> D[m][n]=m exactly ----
  bool isM2;
  {
    f64x4 pr = (f64x4){0., 0., 0., 0.};
    double pa = (double)lm;
    double pb = (kq == 0) ? 1.0 : 0.0;
    pr = __builtin_amdgcn_mfma_f64_16x16x4f64(pa, pb, pr, 0, 0, 0);
    double v = __builtin_amdgcn_readfirstlane(pr[1]);  // lane0: M1->1, M2->4
    isM2 = (v > 2.5);
  }

  // sIn layout: [ic: stride 176][row(3): stride 56][x: 52]; pad slack zeroed.
  // 176 mod 32 = 16 -> quad aliasing exactly 2-way (free).
  __shared__ float sIn[2][720];
  // sW layout: [(tap*4+ic): stride 72][oc: 64]; 72 mod 32 = 8 -> reads 2-way.
  __shared__ float sW[2][2592];

  for (int e = t; e < 2 * 720; e += 256) ((float*)sIn)[e] = 0.f;
  __syncthreads();

  f64x4 acc[4];
  #pragma unroll
  for (int nt = 0; nt < 4; nt++) acc[nt] = (f64x4){0., 0., 0., 0.};

  int pbase[4];
  #pragma unroll
  for (int nt = 0; nt < 4; nt++) {
    int p = nt * 16 + lm;               // px; p>=50 lanes read junk, discarded
    pbase[nt] = kq * 176 + p;
  }

  float xr[3], wr9[9];
  // ---- load chunk 0 into registers ----
  #pragma unroll
  for (int k = 0; k < 3; k++) {
    int e = t + k * 256;
    float v = 0.f;
    if (e < 624) {
      int ic = e / 156, rem = e - ic * 156;
      int r = rem / 52, xx = rem - r * 52;
      int yy = y0 + r - 1, xc = xx - 1;
      if (yy >= 0 && yy < 50 && xc >= 0 && xc < 50)
        v = xg[(((size_t)n * 512 + ic) * 50 + yy) * 50 + xc];
    }
    xr[k] = v;
  }
  #pragma unroll
  for (int k = 0; k < 9; k++) {
    int e = t + k * 256;
    int oc = e / 36, rem = e - oc * 36;
    int ic = rem / 9, tap = rem - ic * 9;
    wr9[k] = wg[((size_t)(oc0 + oc) * 512 + ic) * 9 + tap];
  }
  // ---- store chunk 0 into buffer 0 ----
  #pragma unroll
  for (int k = 0; k < 3; k++) {
    int e = t + k * 256;
    if (e < 624) {
      int ic = e / 156, rem = e - ic * 156;
      int r = rem / 52, xx = rem - r * 52;
      sIn[0][ic * 176 + r * 56 + xx] = xr[k];
    }
  }
  #pragma unroll
  for (int k = 0; k < 9; k++) {
    int e = t + k * 256;
    int oc = e / 36, rem = e - oc * 36;
    int ic = rem / 9, tap = rem - ic * 9;
    sW[0][(tap * 4 + ic) * 72 + oc] = wr9[k];
  }

  for (int c = 0; c < 128; c++) {
    __syncthreads();                      // buf[c&1] ready for all waves
    const int cur = c & 1, nxt = cur ^ 1;
    const int ic0n = (c + 1) * 4;
    if (c + 1 < 128) {                    // issue global loads for chunk c+1
      #pragma unroll
      for (int k = 0; k < 3; k++) {
        int e = t + k * 256;
        float v = 0.f;
        if (e < 624) {
          int ic = e / 156, rem = e - ic * 156;
          int r = rem / 52, xx = rem - r * 52;
          int yy = y0 + r - 1, xc = xx - 1;
          if (yy >= 0 && yy < 50 && xc >= 0 && xc < 50)
            v = xg[(((size_t)n * 512 + ic0n + ic) * 50 + yy) * 50 + xc];
        }
        xr[k] = v;
      }
      #pragma unroll
      for (int k = 0; k < 9; k++) {
        int e = t + k * 256;
        int oc = e / 36, rem = e - oc * 36;
        int ic = rem / 9, tap = rem - ic * 9;
        wr9[k] = wg[((size_t)(oc0 + oc) * 512 + ic0n + ic) * 9 + tap];
      }
    }
    // ---- compute on buf[cur] (overlaps the loads above) ----
    #pragma unroll
    for (int tap = 0; tap < 9; tap++) {
      const int ky = tap / 3, kx = tap - ky * 3;
      const double a = (double)sW[cur][(tap * 4 + kq) * 72 + wv * 16 + lm];
      const int off = ky * 56 + kx;
      #pragma unroll
      for (int nt = 0; nt < 4; nt++) {
        const double b = (double)sIn[cur][pbase[nt] + off];
        acc[nt] = __builtin_amdgcn_mfma_f64_16x16x4f64(a, b, acc[nt], 0, 0, 0);
      }
    }
    // ---- store chunk c+1 into buf[nxt] ----
    if (c + 1 < 128) {
      #pragma unroll
      for (int k = 0; k < 3; k++) {
        int e = t + k * 256;
        if (e < 624) {
          int ic = e / 156, rem = e - ic * 156;
          int r = rem / 52, xx = rem - r * 52;
          sIn[nxt][ic * 176 + r * 56 + xx] = xr[k];
        }
      }
      #pragma unroll
      for (int k = 0; k < 9; k++) {
        int e = t + k * 256;
        int oc = e / 36, rem = e - oc * 36;
        int ic = rem / 9, tap = rem - ic * 9;
        sW[nxt][(tap * 4 + ic) * 72 + oc] = wr9[k];
      }
    }
  }

  // epilogue: bias + relu (f64); row mapping per probe
  #pragma unroll
  for (int nt = 0; nt < 4; nt++) {
    int p = nt * 16 + lm;
    if (p < 50) {
      #pragma unroll
      for (int i = 0; i < 4; i++) {
        int row = isM2 ? (kq + 4 * i) : (kq * 4 + i);
        int oc = oc0 + wv * 16 + row;
        featD[(((size_t)n * 512 + oc) * 50 + y0) * 50 + p] =
            fmax(acc[nt][i] + (double)bg[oc], 0.0);
      }
    }
  }
}

// ======================= 1x1 heads (loc 36 + score 18), f64 =================
// weights staged in LDS (reads are wave-uniform -> broadcast, conflict-free)
__global__ __launch_bounds__(256) void heads_kernel(
    const double* __restrict__ featD,
    const float* __restrict__ loc_w, const float* __restrict__ loc_b,
    const float* __restrict__ score_w, const float* __restrict__ score_b,
    double* __restrict__ locD, double* __restrict__ scoreD,
    float* __restrict__ out)
{
  const int p = blockIdx.x * 256 + threadIdx.x;
  const int ocg = blockIdx.y;
  const int n = blockIdx.z;
  const bool pv = (p < 2500);
  const int pp = pv ? p : 0;
  const double* fbase = featD + (size_t)n * 512 * 2500 + pp;

  __shared__ float wsh[8 * 512];
  double bias[8];
  #pragma unroll
  for (int jj = 0; jj < 8; jj++) {
    int oc = ocg * 8 + jj;
    int occ = (oc < 54) ? oc : 0;
    bias[jj] = (occ < 36) ? (double)loc_b[occ] : (double)score_b[occ - 36];
  }
  for (int e = threadIdx.x; e < 8 * 512; e += 256) {
    int jj = e >> 9, c = e & 511;
    int oc = ocg * 8 + jj;
    int occ = (oc < 54) ? oc : 0;
    wsh[e] = (occ < 36) ? loc_w[(size_t)occ * 512 + c]
                        : score_w[(size_t)(occ - 36) * 512 + c];
  }
  __syncthreads();

  double acc[8] = {0, 0, 0, 0, 0, 0, 0, 0};
  #pragma unroll 4
  for (int c = 0; c < 512; c++) {
    double f = fbase[(size_t)c * 2500];
    #pragma unroll
    for (int jj = 0; jj < 8; jj++) acc[jj] += f * (double)wsh[jj * 512 + c];
  }
  if (!pv) return;
  #pragma unroll
  for (int jj = 0; jj < 8; jj++) {
    int oc = ocg * 8 + jj;
    if (oc >= 54) break;
    double v = acc[jj] + bias[jj];
    if (oc < 36) {
      locD[(size_t)n * 90000 + (size_t)p * 36 + oc] = v;
      out[(size_t)n * 90000 + (size_t)p * 36 + oc] = (float)v;
    } else {
      scoreD[(size_t)n * 45000 + (size_t)p * 18 + (oc - 36)] = v;
      out[360000 + (size_t)n * 45000 + (size_t)p * 18 + (oc - 36)] = (float)v;
    }
  }
}

// robust scalar decode: harness may deliver python ints as int32 or float32
__device__ inline double decode_dim(const int* p) {
  int v = p[0];
  if (v > 0 && v < 1000000) return (double)v;
  return (double)__int_as_float(v);
}

// ======================= zero ws counters (after heads; aliases featD) =======
__global__ void zero_kernel(unsigned* __restrict__ hist, int* __restrict__ sValid,
                            unsigned* __restrict__ cnt)
{
  const int i = blockIdx.x * 256 + threadIdx.x;
  if (i < 262144) hist[i] = 0u;
  if (i < 12000) sValid[i] = 0;
  if (i < 4) cnt[i] = 0u;
}

// ======================= anchors + loc2bbox + clip + valid + fg (f64) ========
__global__ void prep_kernel(const double* __restrict__ locD,
                            const double* __restrict__ scoreD,
                            const int* __restrict__ img_h_p, const int* __restrict__ img_w_p,
                            double* __restrict__ roiD, double* __restrict__ selD,
                            unsigned* __restrict__ hist, float* __restrict__ d_out)
{
  const int i = blockIdx.x * 256 + threadIdx.x;
  const int n = blockIdx.y;
  if (i >= 22500) return;
  const int p = i / 9, ab = i - p * 9;
  const int y = p / 50, x = p - y * 50;
  const int ri = ab / 3, sidx = ab - ri * 3;
  const double rr = (ri == 0) ? 0.5 : (ri == 1 ? 1.0 : 2.0);
  const double sc = (sidx == 0) ? 8.0 : (sidx == 1 ? 16.0 : 32.0);
  const double hh = 16.0 * sc * sqrt(rr);
  const double wd = 16.0 * sc * sqrt(1.0 / rr);
  const float bx1 = (float)(8.0 - wd * 0.5), by1 = (float)(8.0 - hh * 0.5);
  const float bx2 = (float)(8.0 + wd * 0.5), by2 = (float)(8.0 + hh * 0.5);
  const float sxf = (float)(x * 16), syf = (float)(y * 16);
  const float ax1 = bx1 + sxf, ay1 = by1 + syf, ax2 = bx2 + sxf, ay2 = by2 + syf;
  if (n == 0) {
    ((float4*)(d_out + 546000))[i] = make_float4(ax1, ay1, ax2, ay2);
  }
  const double l0 = locD[(size_t)n * 90000 + (size_t)i * 4 + 0];
  const double l1 = locD[(size_t)n * 90000 + (size_t)i * 4 + 1];
  const double l2 = locD[(size_t)n * 90000 + (size_t)i * 4 + 2];
  const double l3 = locD[(size_t)n * 90000 + (size_t)i * 4 + 3];
  const double s0 = scoreD[(size_t)n * 45000 + (size_t)i * 2 + 0];
  const double s1 = scoreD[(size_t)n * 45000 + (size_t)i * 2 + 1];
  const double aw = (double)ax2 - (double)ax1, ah = (double)ay2 - (double)ay1;
  const double acx = (double)ax1 + 0.5 * aw, acy = (double)ay1 + 0.5 * ah;
  const double cx = l0 * aw + acx, cy = l1 * ah + acy;
  const double ww = exp(l2) * aw, hh2 = exp(l3) * ah;
  double x1 = cx - 0.5 * ww, y1 = cy - 0.5 * hh2;
  double x2 = cx + 0.5 * ww, y2 = cy + 0.5 * hh2;
  const double fw = decode_dim(img_w_p), fh = decode_dim(img_h_p);
  x1 = fmin(fmax(x1, 0.0), fw); x2 = fmin(fmax(x2, 0.0), fw);
  y1 = fmin(fmax(y1, 0.0), fh); y2 = fmin(fmax(y2, 0.0), fh);
  const bool valid = (x2 - x1 + 1.0 >= 16.0) && (y2 - y1 + 1.0 >= 16.0);
  const double m = fmax(s0, s1);
  const double e0 = exp(s0 - m), e1 = exp(s1 - m);
  const double fg = e1 / (e0 + e1);
  double* rb = roiD + ((size_t)n * 22500 + i) * 4;
  rb[0] = x1; rb[1] = y1; rb[2] = x2; rb[3] = y2;
  selD[(size_t)n * 22500 + i] = valid ? fg : -INFINITY;
  if (valid) {  // fg in (0,1): positive f64 -> bits order == value order
    unsigned key = (unsigned)((unsigned long long)__double_as_longlong(fg) >> 48);
    atomicAdd(&hist[n * 65536 + key], 1u);
  }
}

// ======================= threshold: largest key class covering top-3000 ======
__global__ __launch_bounds__(256) void thresh_kernel(
    const unsigned* __restrict__ hist, unsigned* __restrict__ thrP)
{
  const int n = blockIdx.x;
  const int t = threadIdx.x;
  __shared__ unsigned csum[256];
  const unsigned* h = hist + (size_t)n * 65536;
  unsigned s = 0;
  for (int k = 0; k < 256; k++) s += h[t * 256 + k];
  csum[t] = s;
  __syncthreads();
  if (t == 0) {
    unsigned suf = 0, Tkey = 0;
    for (int c = 255; c >= 0; c--) {
      if (suf + csum[c] >= 3000u) {
        for (int v = c * 256 + 255; v >= c * 256; v--) {
          suf += h[v];
          if (suf >= 3000u) { Tkey = (unsigned)v; break; }
        }
        break;
      }
      suf += csum[c];
    }
    thrP[n] = Tkey;   // 0 if <3000 valid -> all valid become candidates
  }
}

// ======================= compact candidates (key >= threshold) ===============
__global__ void compact_kernel(const double* __restrict__ selD,
                               const unsigned* __restrict__ thrP,
                               unsigned* __restrict__ cnt,
                               int* __restrict__ candIdx, double* __restrict__ candS)
{
  const int i = blockIdx.x * 256 + threadIdx.x;
  const int n = blockIdx.y;
  if (i >= 22500) return;
  const double s = selD[(size_t)n * 22500 + i];
  if (!(s > -INFINITY)) return;
  unsigned key = (unsigned)((unsigned long long)__double_as_longlong(s) >> 48);
  if (key < thrP[n]) return;
  unsigned pos = atomicAdd(&cnt[n], 1u);
  candIdx[(size_t)n * 22500 + pos] = i;
  candS[(size_t)n * 22500 + pos] = s;
}

// ======================= exact rank among candidates (= lax.top_k order) =====
__global__ __launch_bounds__(256) void crank_kernel(
    const unsigned* __restrict__ cnt, const int* __restrict__ candIdx,
    const double* __restrict__ candS, const double* __restrict__ roiD,
    double* __restrict__ sBoxD, int* __restrict__ sValid)
{
  const int n = blockIdx.y;
  const int m = (int)cnt[n];
  if ((int)(blockIdx.x * 256) >= m) return;   // block-uniform early exit
  const int tid = blockIdx.x * 256 + threadIdx.x;
  const bool act = (tid < m);
  const double si = act ? candS[(size_t)n * 22500 + tid] : 0.0;
  const int ii = act ? candIdx[(size_t)n * 22500 + tid] : 0x7fffffff;
  __shared__ double sv[256];
  __shared__ int siv[256];
  int rank = 0;
  for (int j0 = 0; j0 < m; j0 += 256) {
    __syncthreads();
    const int jl = j0 + threadIdx.x;
    if (jl < m) {
      sv[threadIdx.x] = candS[(size_t)n * 22500 + jl];
      siv[threadIdx.x] = candIdx[(size_t)n * 22500 + jl];
    }
    __syncthreads();
    const int lim = (m - j0 < 256) ? (m - j0) : 256;
    for (int k = 0; k < lim; k++) {
      const double sj = sv[k];
      const int ij = siv[k];
      rank += ((sj > si) || (sj == si && ij < ii)) ? 1 : 0;
    }
  }
  if (act && rank < 3000) {
    const double* rb = roiD + ((size_t)n * 22500 + ii) * 4;
    double* db = sBoxD + ((size_t)n * 3000 + rank) * 4;
    db[0] = rb[0]; db[1] = rb[1]; db[2] = rb[2]; db[3] = rb[3];
    sValid[n * 3000 + rank] = 1;
  }
}

// ======================= NMS phase A: suppression bitmask (f64 IoU) ==========
__global__ void supmat_kernel(const double* __restrict__ sBoxD,
                              unsigned long long* __restrict__ sup)
{
  const int wj = blockIdx.x, ig = blockIdx.y, n = blockIdx.z;
  const int lane = threadIdx.x;
  const int i = ig * 64 + lane;
  if (wj < ig) {                       // strictly below diagonal: all zero
    if (i < 3000) sup[((size_t)n * 3000 + i) * 47 + wj] = 0ull;
    return;
  }
  __shared__ double jb[64][4];
  const int j0 = wj * 64;
  {
    int j = j0 + lane;
    if (j < 3000) {
      const double* b = sBoxD + ((size_t)n * 3000 + j) * 4;
      jb[lane][0] = b[0]; jb[lane][1] = b[1]; jb[lane][2] = b[2]; jb[lane][3] = b[3];
    } else {
      jb[lane][0] = 0; jb[lane][1] = 0; jb[lane][2] = 0; jb[lane][3] = 0;
    }
  }
  __syncthreads();
  if (i >= 3000) return;
  const double* bi = sBoxD + ((size_t)n * 3000 + i) * 4;
  const double bx1 = bi[0], by1 = bi[1], bx2 = bi[2], by2 = bi[3];
  const double ai = (bx2 - bx1) * (by2 - by1);
  unsigned long long msk = 0;
  #pragma unroll 2
  for (int tt = 0; tt < 64; tt++) {
    const int j = j0 + tt;
    const double jx1 = jb[tt][0], jy1 = jb[tt][1], jx2 = jb[tt][2], jy2 = jb[tt][3];
    double iw = fmax(fmin(bx2, jx2) - fmax(bx1, jx1), 0.0);
    double ih = fmax(fmin(by2, jy2) - fmax(by1, jy1), 0.0);
    double inter = iw * ih;
    double aj = (jx2 - jx1) * (jy2 - jy1);
    double iou = inter / (ai + aj - inter + 1e-9);
    if (iou > 0.7 && j > i && j < 3000) msk |= (1ull << tt);
  }
  sup[((size_t)n * 3000 + i) * 47 + wj] = msk;
}

// ======================= NMS phase B: scan + outputs =======================
#define SCAN_DEPTH 12   // 3000 = 12 * 250
__global__ void nms_scan_kernel(const double* __restrict__ sBoxD,
                                const int* __restrict__ sValid,
                                const unsigned long long* __restrict__ sup,
                                float* __restrict__ out)
{
  const int n = blockIdx.x;
  const int lane = threadIdx.x;
  unsigned long long alive = 0;
  for (int w = 0; w < 47; w++) {
    int idx = w * 64 + lane;
    int v = (idx < 3000) ? sValid[(size_t)n * 3000 + idx] : 0;
    unsigned long long bm = __ballot(v != 0);
    if (lane == w) alive = bm;
  }
  const unsigned long long* srow = sup + (size_t)n * 3000 * 47;
  const bool ld = (lane < 47);
  unsigned long long buf[SCAN_DEPTH];
  #pragma unroll
  for (int d = 0; d < SCAN_DEPTH; d++)
    buf[d] = ld ? srow[(size_t)d * 47 + lane] : 0ull;
  for (int ib = 0; ib < 3000; ib += SCAN_DEPTH) {
    #pragma unroll
    for (int d = 0; d < SCAN_DEPTH; d++) {
      const int i = ib + d;
      const unsigned long long row = buf[d];
      const int pf = i + SCAN_DEPTH;
      buf[d] = (ld && pf < 3000) ? srow[(size_t)pf * 47 + lane] : 0ull;
      const unsigned long long aw = __shfl(alive, i >> 6);
      if ((aw >> (i & 63)) & 1ull) alive &= ~row;
    }
  }
  int c = __popcll(alive);
  int pre = c;
  #pragma unroll
  for (int off = 1; off < 64; off <<= 1) {
    int t2 = __shfl_up(pre, off);
    if (lane >= off) pre += t2;
  }
  const int excl = pre - c;
  const int tot = __shfl(pre, 63);
  float4* rois4 = (float4*)(out + 540000);
  unsigned long long a = alive;
  int r = excl;
  while (a) {
    int b = __ffsll((unsigned long long)a) - 1;
    a &= (a - 1);
    if (r < 300) {
      int i = lane * 64 + b;
      const double* bb = sBoxD + ((size_t)n * 3000 + i) * 4;
      rois4[n * 300 + r] = make_float4((float)bb[0], (float)bb[1],
                                       (float)bb[2], (float)bb[3]);
    }
    r++;
  }
  for (int k = tot + lane; k < 300; k += 64)
    rois4[n * 300 + k] = make_float4(0, 0, 0, 0);
  for (int k = lane; k < 300; k += 64)
    out[544800 + n * 300 + k] = (float)n;
}

// ======================= launch =======================
extern "C" void kernel_launch(void* const* d_in, const int* in_sizes, int n_in,
                              void* d_out, int out_size, void* d_ws, size_t ws_size,
                              hipStream_t stream) {
  const float* x        = (const float*)d_in[0];
  const float* conv1_w  = (const float*)d_in[1];
  const float* conv1_b  = (const float*)d_in[2];
  const float* loc_w    = (const float*)d_in[3];
  const float* loc_b    = (const float*)d_in[4];
  const float* score_w  = (const float*)d_in[5];
  const float* score_b  = (const float*)d_in[6];
  const int*   img_h    = (const int*)d_in[7];
  const int*   img_w    = (const int*)d_in[8];
  float* out = (float*)d_out;
  char* ws = (char*)d_ws;

  // live ranges: featD conv->heads only; then its region is recycled.
  double* featD  = (double*)(ws);                  // [0, 40,960,000)
  double* locD   = (double*)(ws + 40960000);       // +2,880,000
  double* scoreD = (double*)(ws + 43840000);       // +1,440,000 -> 45,280,000
  // aliases into featD's dead region (all used strictly after heads_kernel):
  double* roiD   = (double*)(ws);                  // [0, 2,880,000)
  double* selD   = (double*)(ws + 2880000);        // +720,000
  double* sBoxD  = (double*)(ws + 3600000);        // +384,000
  int*    sValid = (int*)(ws + 4000000);           // +48,000
  unsigned long long* sup = (unsigned long long*)(ws + 4100000);  // +4,512,000
  unsigned* hist   = (unsigned*)(ws + 8700000);    // +1,048,576
  unsigned* cnt    = (unsigned*)(ws + 9750000);    // +16
  unsigned* thrP   = (unsigned*)(ws + 9751040);    // +16
  int*      candIdx= (int*)(ws + 9752000);         // +360,000
  double*   candS  = (double*)(ws + 10200000);     // +720,000 -> 10,920,000

  conv3x3_kernel<<<dim3(50, 8, 4), 256, 0, stream>>>(x, conv1_w, conv1_b, featD);
  heads_kernel<<<dim3(10, 7, 4), 256, 0, stream>>>(featD, loc_w, loc_b, score_w, score_b,
                                                   locD, scoreD, out);
  zero_kernel<<<1024, 256, 0, stream>>>(hist, sValid, cnt);
  prep_kernel<<<dim3(88, 4), 256, 0, stream>>>(locD, scoreD, img_h, img_w,
                                               roiD, selD, hist, out);
  thresh_kernel<<<4, 256, 0, stream>>>(hist, thrP);
  compact_kernel<<<dim3(88, 4), 256, 0, stream>>>(selD, thrP, cnt, candIdx, candS);
  crank_kernel<<<dim3(88, 4), 256, 0, stream>>>(cnt, candIdx, candS, roiD, sBoxD, sValid);
  supmat_kernel<<<dim3(47, 47, 4), 64, 0, stream>>>(sBoxD, sup);
  nms_scan_kernel<<<4, 64, 0, stream>>>(sBoxD, sValid, sup, out);
}

// Round 11
// 2483.574 us; speedup vs baseline: 2.2223x; 1.0065x over previous
//
#include <hip/hip_runtime.h>
#include <hip/hip_bf16.h>
#include <math.h>

// ---------------- problem constants ----------------
// x: (4,512,50,50) f32; conv1_w: (512,512,3,3); heads: 36 loc + 18 score ch
// outputs (f32, concat): rpn_locs 360000 | rpn_scores 180000 @360000 |
//   rois 4800 @540000 | roi_indices 1200 @544800 | anchor 90000 @546000
//
// Numerics: proposal path f64 end-to-end (ref=np is f64).
// R11: (1) conv sW re-laid oc-major stride-37: staging ds_writes were 4-way+
// bank-conflicted (72*4 = 0 mod 128) = 28% of the MFMA round; (2) heads
// restructured to 27-oc x 128-c tiles + f64 atomicAdd into bias-initialized
// locD/scoreD (featD HBM traffic 287->80 MB; f32 out-writes moved to prep);
// (3) thresh scan reads staged through LDS.

typedef double f64x4 __attribute__((ext_vector_type(4)));

// ======================= conv 3x3 via f64 MFMA, double-buffered =============
// block 256 thr = 4 waves; tile 64 oc x 50 px (1 row); grid (50,8,4).
// Per MFMA: A=W[16 oc][4 ic] (lane=16k+m), B=X[4 ic][16 px] (lane=16k+n).
__global__ __launch_bounds__(256) void conv3x3_kernel(
    const float* __restrict__ xg, const float* __restrict__ wg,
    const float* __restrict__ bg, double* __restrict__ featD)
{
  const int y0 = blockIdx.x, ocb = blockIdx.y, n = blockIdx.z;
  const int t = threadIdx.x;
  const int lane = t & 63;
  const int wv = t >> 6;          // wave id 0..3 -> oc group
  const int lm = lane & 15;       // m (A) / n (B) within tile
  const int kq = lane >> 4;       // k 0..3
  const int oc0 = ocb * 64;

  // ---- C/D layout probe: A[m][k]=m, B[k][n]=(k==0) -> D[m][n]=m exactly ----
  bool isM2;
  {
    f64x4 pr = (f64x4){0., 0., 0., 0.};
    double pa = (double)lm;
    double pb = (kq == 0) ? 1.0 : 0.0;
    pr = __builtin_amdgcn_mfma_f64_16x16x4f64(pa, pb, pr, 0, 0, 0);
    double v = __builtin_amdgcn_readfirstlane(pr[1]);  // lane0: M1->1, M2->4
    isM2 = (v > 2.5);
  }

  // sIn: [ic: stride 176][row(3): stride 56][x: 52]; 176 mod 32 = 16 -> 2-way.
  __shared__ float sIn[2][720];
  // sW: [oc: stride 37][row = tap*4+ic (36)]; writes lane-consecutive
  // (conflict-free), reads (5*lm+4*kq) mod 32 -> <=2-way (free).
  __shared__ float sW[2][2368];

  for (int e = t; e < 2 * 720; e += 256) ((float*)sIn)[e] = 0.f;
  __syncthreads();

  f64x4 acc[4];
  #pragma unroll
  for (int nt = 0; nt < 4; nt++) acc[nt] = (f64x4){0., 0., 0., 0.};

  int pbase[4];
  #pragma unroll
  for (int nt = 0; nt < 4; nt++) {
    int p = nt * 16 + lm;               // px; p>=50 lanes read junk, discarded
    pbase[nt] = kq * 176 + p;
  }

  float xr[3], wr9[9];
  // ---- load chunk 0 into registers ----
  #pragma unroll
  for (int k = 0; k < 3; k++) {
    int e = t + k * 256;
    float v = 0.f;
    if (e < 624) {
      int ic = e / 156, rem = e - ic * 156;
      int r = rem / 52, xx = rem - r * 52;
      int yy = y0 + r - 1, xc = xx - 1;
      if (yy >= 0 && yy < 50 && xc >= 0 && xc < 50)
        v = xg[(((size_t)n * 512 + ic) * 50 + yy) * 50 + xc];
    }
    xr[k] = v;
  }
  #pragma unroll
  for (int k = 0; k < 9; k++) {
    int e = t + k * 256;
    int oc = e / 36, rem = e - oc * 36;
    int ic = rem / 9, tap = rem - ic * 9;
    wr9[k] = wg[((size_t)(oc0 + oc) * 512 + ic) * 9 + tap];
  }
  // ---- store chunk 0 into buffer 0 ----
  #pragma unroll
  for (int k = 0; k < 3; k++) {
    int e = t + k * 256;
    if (e < 624) {
      int ic = e / 156, rem = e - ic * 156;
      int r = rem / 52, xx = rem - r * 52;
      sIn[0][ic * 176 + r * 56 + xx] = xr[k];
    }
  }
  #pragma unroll
  for (int k = 0; k < 9; k++) {
    int e = t + k * 256;
    int oc = e / 36, rem = e - oc * 36;
    int ic = rem / 9, tap = rem - ic * 9;
    sW[0][oc * 37 + tap * 4 + ic] = wr9[k];
  }

  for (int c = 0; c < 128; c++) {
    __syncthreads();                      // buf[c&1] ready for all waves
    const int cur = c & 1, nxt = cur ^ 1;
    const int ic0n = (c + 1) * 4;
    if (c + 1 < 128) {                    // issue global loads for chunk c+1
      #pragma unroll
      for (int k = 0; k < 3; k++) {
        int e = t + k * 256;
        float v = 0.f;
        if (e < 624) {
          int ic = e / 156, rem = e - ic * 156;
          int r = rem / 52, xx = rem - r * 52;
          int yy = y0 + r - 1, xc = xx - 1;
          if (yy >= 0 && yy < 50 && xc >= 0 && xc < 50)
            v = xg[(((size_t)n * 512 + ic0n + ic) * 50 + yy) * 50 + xc];
        }
        xr[k] = v;
      }
      #pragma unroll
      for (int k = 0; k < 9; k++) {
        int e = t + k * 256;
        int oc = e / 36, rem = e - oc * 36;
        int ic = rem / 9, tap = rem - ic * 9;
        wr9[k] = wg[((size_t)(oc0 + oc) * 512 + ic0n + ic) * 9 + tap];
      }
    }
    // ---- compute on buf[cur] (overlaps the loads above) ----
    #pragma unroll
    for (int tap = 0; tap < 9; tap++) {
      const int ky = tap / 3, kx = tap - ky * 3;
      const double a = (double)sW[cur][(wv * 16 + lm) * 37 + tap * 4 + kq];
      const int off = ky * 56 + kx;
      #pragma unroll
      for (int nt = 0; nt < 4; nt++) {
        const double b = (double)sIn[cur][pbase[nt] + off];
        acc[nt] = __builtin_amdgcn_mfma_f64_16x16x4f64(a, b, acc[nt], 0, 0, 0);
      }
    }
    // ---- store chunk c+1 into buf[nxt] ----
    if (c + 1 < 128) {
      #pragma unroll
      for (int k = 0; k < 3; k++) {
        int e = t + k * 256;
        if (e < 624) {
          int ic = e / 156, rem = e - ic * 156;
          int r = rem / 52, xx = rem - r * 52;
          sIn[nxt][ic * 176 + r * 56 + xx] = xr[k];
        }
      }
      #pragma unroll
      for (int k = 0; k < 9; k++) {
        int e = t + k * 256;
        int oc = e / 36, rem = e - oc * 36;
        int ic = rem / 9, tap = rem - ic * 9;
        sW[nxt][oc * 37 + tap * 4 + ic] = wr9[k];
      }
    }
  }

  // epilogue: bias + relu (f64); row mapping per probe
  #pragma unroll
  for (int nt = 0; nt < 4; nt++) {
    int p = nt * 16 + lm;
    if (p < 50) {
      #pragma unroll
      for (int i = 0; i < 4; i++) {
        int row = isM2 ? (kq + 4 * i) : (kq * 4 + i);
        int oc = oc0 + wv * 16 + row;
        featD[(((size_t)n * 512 + oc) * 50 + y0) * 50 + p] =
            fmax(acc[nt][i] + (double)bg[oc], 0.0);
      }
    }
  }
}

// ======================= heads init: locD/scoreD = bias ======================
__global__ void heads_init_kernel(const float* __restrict__ loc_b,
                                  const float* __restrict__ score_b,
                                  double* __restrict__ locD,
                                  double* __restrict__ scoreD)
{
  const int i = blockIdx.x * 256 + threadIdx.x;
  if (i < 360000) locD[i] = (double)loc_b[i % 36];
  else if (i < 540000) {
    int j = i - 360000;
    scoreD[j] = (double)score_b[j % 18];
  }
}

// ======================= 1x1 heads: 27 oc x 128 c tiles, atomic f64 ==========
// grid (10, 8, 4): y = ocg*4 + chunk; featD read exactly twice (80 MB).
__global__ __launch_bounds__(256) void heads_kernel(
    const double* __restrict__ featD,
    const float* __restrict__ loc_w, const float* __restrict__ score_w,
    double* __restrict__ locD, double* __restrict__ scoreD)
{
  const int p = blockIdx.x * 256 + threadIdx.x;
  const int ocg = blockIdx.y >> 2;       // 0..1 -> oc base 0 / 27
  const int ch = blockIdx.y & 3;         // c chunk 0..3
  const int n = blockIdx.z;
  const int oc0 = ocg * 27;
  const int c0 = ch * 128;

  __shared__ float wsh[27 * 128];
  for (int e = threadIdx.x; e < 27 * 128; e += 256) {
    int jj = e >> 7, cc = e & 127;
    int oc = oc0 + jj;
    wsh[e] = (oc < 36) ? loc_w[(size_t)oc * 512 + c0 + cc]
                       : score_w[(size_t)(oc - 36) * 512 + c0 + cc];
  }
  __syncthreads();
  const bool pv = (p < 2500);
  const int pp = pv ? p : 0;
  const double* fbase = featD + (size_t)n * 512 * 2500 + (size_t)c0 * 2500 + pp;

  double acc[27];
  #pragma unroll
  for (int jj = 0; jj < 27; jj++) acc[jj] = 0.0;
  #pragma unroll 4
  for (int cc = 0; cc < 128; cc++) {
    double f = fbase[(size_t)cc * 2500];
    #pragma unroll
    for (int jj = 0; jj < 27; jj++) acc[jj] += f * (double)wsh[jj * 128 + cc];
  }
  if (!pv) return;
  #pragma unroll
  for (int jj = 0; jj < 27; jj++) {
    int oc = oc0 + jj;
    if (oc < 36)
      atomicAdd(&locD[(size_t)n * 90000 + (size_t)p * 36 + oc], acc[jj]);
    else
      atomicAdd(&scoreD[(size_t)n * 45000 + (size_t)p * 18 + (oc - 36)], acc[jj]);
  }
}

// robust scalar decode: harness may deliver python ints as int32 or float32
__device__ inline double decode_dim(const int* p) {
  int v = p[0];
  if (v > 0 && v < 1000000) return (double)v;
  return (double)__int_as_float(v);
}

// ======================= zero ws counters =======
__global__ void zero_kernel(unsigned* __restrict__ hist, int* __restrict__ sValid,
                            unsigned* __restrict__ cnt)
{
  const int i = blockIdx.x * 256 + threadIdx.x;
  if (i < 262144) hist[i] = 0u;
  if (i < 12000) sValid[i] = 0;
  if (i < 4) cnt[i] = 0u;
}

// ======================= anchors + loc2bbox + f32 outputs + fg (f64) =========
// also writes the f32 rpn_locs / rpn_scores outputs (moved from heads).
__global__ void prep_kernel(const double* __restrict__ locD,
                            const double* __restrict__ scoreD,
                            const int* __restrict__ img_h_p, const int* __restrict__ img_w_p,
                            double* __restrict__ roiD, double* __restrict__ selD,
                            unsigned* __restrict__ hist, float* __restrict__ d_out)
{
  const int i = blockIdx.x * 256 + threadIdx.x;
  const int n = blockIdx.y;
  if (i >= 22500) return;
  const int p = i / 9, ab = i - p * 9;
  const int y = p / 50, x = p - y * 50;
  const int ri = ab / 3, sidx = ab - ri * 3;
  const double rr = (ri == 0) ? 0.5 : (ri == 1 ? 1.0 : 2.0);
  const double sc = (sidx == 0) ? 8.0 : (sidx == 1 ? 16.0 : 32.0);
  const double hh = 16.0 * sc * sqrt(rr);
  const double wd = 16.0 * sc * sqrt(1.0 / rr);
  const float bx1 = (float)(8.0 - wd * 0.5), by1 = (float)(8.0 - hh * 0.5);
  const float bx2 = (float)(8.0 + wd * 0.5), by2 = (float)(8.0 + hh * 0.5);
  const float sxf = (float)(x * 16), syf = (float)(y * 16);
  const float ax1 = bx1 + sxf, ay1 = by1 + syf, ax2 = bx2 + sxf, ay2 = by2 + syf;
  if (n == 0) {
    ((float4*)(d_out + 546000))[i] = make_float4(ax1, ay1, ax2, ay2);
  }
  const double l0 = locD[(size_t)n * 90000 + (size_t)i * 4 + 0];
  const double l1 = locD[(size_t)n * 90000 + (size_t)i * 4 + 1];
  const double l2 = locD[(size_t)n * 90000 + (size_t)i * 4 + 2];
  const double l3 = locD[(size_t)n * 90000 + (size_t)i * 4 + 3];
  const double s0 = scoreD[(size_t)n * 45000 + (size_t)i * 2 + 0];
  const double s1 = scoreD[(size_t)n * 45000 + (size_t)i * 2 + 1];
  // f32 outputs (rounded once from the f64 values)
  ((float4*)(d_out + (size_t)n * 90000))[i] =
      make_float4((float)l0, (float)l1, (float)l2, (float)l3);
  ((float2*)(d_out + 360000 + (size_t)n * 45000))[i] =
      make_float2((float)s0, (float)s1);
  const double aw = (double)ax2 - (double)ax1, ah = (double)ay2 - (double)ay1;
  const double acx = (double)ax1 + 0.5 * aw, acy = (double)ay1 + 0.5 * ah;
  const double cx = l0 * aw + acx, cy = l1 * ah + acy;
  const double ww = exp(l2) * aw, hh2 = exp(l3) * ah;
  double x1 = cx - 0.5 * ww, y1 = cy - 0.5 * hh2;
  double x2 = cx + 0.5 * ww, y2 = cy + 0.5 * hh2;
  const double fw = decode_dim(img_w_p), fh = decode_dim(img_h_p);
  x1 = fmin(fmax(x1, 0.0), fw); x2 = fmin(fmax(x2, 0.0), fw);
  y1 = fmin(fmax(y1, 0.0), fh); y2 = fmin(fmax(y2, 0.0), fh);
  const bool valid = (x2 - x1 + 1.0 >= 16.0) && (y2 - y1 + 1.0 >= 16.0);
  const double m = fmax(s0, s1);
  const double e0 = exp(s0 - m), e1 = exp(s1 - m);
  const double fg = e1 / (e0 + e1);
  double* rb = roiD + ((size_t)n * 22500 + i) * 4;
  rb[0] = x1; rb[1] = y1; rb[2] = x2; rb[3] = y2;
  selD[(size_t)n * 22500 + i] = valid ? fg : -INFINITY;
  if (valid) {  // fg in (0,1): positive f64 -> bits order == value order
    unsigned key = (unsigned)((unsigned long long)__double_as_longlong(fg) >> 48);
    atomicAdd(&hist[n * 65536 + key], 1u);
  }
}

// ======================= threshold: largest key class covering top-3000 ======
__global__ __launch_bounds__(256) void thresh_kernel(
    const unsigned* __restrict__ hist, unsigned* __restrict__ thrP)
{
  const int n = blockIdx.x;
  const int t = threadIdx.x;
  __shared__ unsigned csum[256];
  __shared__ unsigned hv[256];
  __shared__ int cstar;
  __shared__ unsigned sufS;
  const unsigned* h = hist + (size_t)n * 65536;
  unsigned s = 0;
  for (int k = 0; k < 256; k++) s += h[t * 256 + k];
  csum[t] = s;
  __syncthreads();
  if (t == 0) {
    unsigned suf = 0; int cs = -1;
    for (int c = 255; c >= 0; c--) {
      if (suf + csum[c] >= 3000u) { cs = c; break; }
      suf += csum[c];
    }
    cstar = cs; sufS = suf;
  }
  __syncthreads();
  const int cs = cstar;
  if (cs >= 0) hv[t] = h[cs * 256 + t];
  __syncthreads();
  if (t == 0) {
    unsigned Tkey = 0;
    if (cs >= 0) {
      unsigned suf = sufS;
      for (int v = 255; v >= 0; v--) {
        suf += hv[v];
        if (suf >= 3000u) { Tkey = (unsigned)(cs * 256 + v); break; }
      }
    }
    thrP[n] = Tkey;   // 0 if <3000 valid -> all valid become candidates
  }
}

// ======================= compact candidates (key >= threshold) ===============
__global__ void compact_kernel(const double* __restrict__ selD,
                               const unsigned* __restrict__ thrP,
                               unsigned* __restrict__ cnt,
                               int* __restrict__ candIdx, double* __restrict__ candS)
{
  const int i = blockIdx.x * 256 + threadIdx.x;
  const int n = blockIdx.y;
  if (i >= 22500) return;
  const double s = selD[(size_t)n * 22500 + i];
  if (!(s > -INFINITY)) return;
  unsigned key = (unsigned)((unsigned long long)__double_as_longlong(s) >> 48);
  if (key < thrP[n]) return;
  unsigned pos = atomicAdd(&cnt[n], 1u);
  candIdx[(size_t)n * 22500 + pos] = i;
  candS[(size_t)n * 22500 + pos] = s;
}

// ======================= exact rank among candidates (= lax.top_k order) =====
__global__ __launch_bounds__(256) void crank_kernel(
    const unsigned* __restrict__ cnt, const int* __restrict__ candIdx,
    const double* __restrict__ candS, const double* __restrict__ roiD,
    double* __restrict__ sBoxD, int* __restrict__ sValid)
{
  const int n = blockIdx.y;
  const int m = (int)cnt[n];
  if ((int)(blockIdx.x * 256) >= m) return;   // block-uniform early exit
  const int tid = blockIdx.x * 256 + threadIdx.x;
  const bool act = (tid < m);
  const double si = act ? candS[(size_t)n * 22500 + tid] : 0.0;
  const int ii = act ? candIdx[(size_t)n * 22500 + tid] : 0x7fffffff;
  __shared__ double sv[256];
  __shared__ int siv[256];
  int rank = 0;
  for (int j0 = 0; j0 < m; j0 += 256) {
    __syncthreads();
    const int jl = j0 + threadIdx.x;
    if (jl < m) {
      sv[threadIdx.x] = candS[(size_t)n * 22500 + jl];
      siv[threadIdx.x] = candIdx[(size_t)n * 22500 + jl];
    }
    __syncthreads();
    const int lim = (m - j0 < 256) ? (m - j0) : 256;
    for (int k = 0; k < lim; k++) {
      const double sj = sv[k];
      const int ij = siv[k];
      rank += ((sj > si) || (sj == si && ij < ii)) ? 1 : 0;
    }
  }
  if (act && rank < 3000) {
    const double* rb = roiD + ((size_t)n * 22500 + ii) * 4;
    double* db = sBoxD + ((size_t)n * 3000 + rank) * 4;
    db[0] = rb[0]; db[1] = rb[1]; db[2] = rb[2]; db[3] = rb[3];
    sValid[n * 3000 + rank] = 1;
  }
}

// ======================= NMS phase A: suppression bitmask (f64 IoU) ==========
__global__ void supmat_kernel(const double* __restrict__ sBoxD,
                              unsigned long long* __restrict__ sup)
{
  const int wj = blockIdx.x, ig = blockIdx.y, n = blockIdx.z;
  const int lane = threadIdx.x;
  const int i = ig * 64 + lane;
  if (wj < ig) {                       // strictly below diagonal: all zero
    if (i < 3000) sup[((size_t)n * 3000 + i) * 47 + wj] = 0ull;
    return;
  }
  __shared__ double jb[64][4];
  const int j0 = wj * 64;
  {
    int j = j0 + lane;
    if (j < 3000) {
      const double* b = sBoxD + ((size_t)n * 3000 + j) * 4;
      jb[lane][0] = b[0]; jb[lane][1] = b[1]; jb[lane][2] = b[2]; jb[lane][3] = b[3];
    } else {
      jb[lane][0] = 0; jb[lane][1] = 0; jb[lane][2] = 0; jb[lane][3] = 0;
    }
  }
  __syncthreads();
  if (i >= 3000) return;
  const double* bi = sBoxD + ((size_t)n * 3000 + i) * 4;
  const double bx1 = bi[0], by1 = bi[1], bx2 = bi[2], by2 = bi[3];
  const double ai = (bx2 - bx1) * (by2 - by1);
  unsigned long long msk = 0;
  #pragma unroll 2
  for (int tt = 0; tt < 64; tt++) {
    const int j = j0 + tt;
    const double jx1 = jb[tt][0], jy1 = jb[tt][1], jx2 = jb[tt][2], jy2 = jb[tt][3];
    double iw = fmax(fmin(bx2, jx2) - fmax(bx1, jx1), 0.0);
    double ih = fmax(fmin(by2, jy2) - fmax(by1, jy1), 0.0);
    double inter = iw * ih;
    double aj = (jx2 - jx1) * (jy2 - jy1);
    double iou = inter / (ai + aj - inter + 1e-9);
    if (iou > 0.7 && j > i && j < 3000) msk |= (1ull << tt);
  }
  sup[((size_t)n * 3000 + i) * 47 + wj] = msk;
}

// ======================= NMS phase B: scan + outputs =======================
#define SCAN_DEPTH 12   // 3000 = 12 * 250
__global__ void nms_scan_kernel(const double* __restrict__ sBoxD,
                                const int* __restrict__ sValid,
                                const unsigned long long* __restrict__ sup,
                                float* __restrict__ out)
{
  const int n = blockIdx.x;
  const int lane = threadIdx.x;
  unsigned long long alive = 0;
  for (int w = 0; w < 47; w++) {
    int idx = w * 64 + lane;
    int v = (idx < 3000) ? sValid[(size_t)n * 3000 + idx] : 0;
    unsigned long long bm = __ballot(v != 0);
    if (lane == w) alive = bm;
  }
  const unsigned long long* srow = sup + (size_t)n * 3000 * 47;
  const bool ld = (lane < 47);
  unsigned long long buf[SCAN_DEPTH];
  #pragma unroll
  for (int d = 0; d < SCAN_DEPTH; d++)
    buf[d] = ld ? srow[(size_t)d * 47 + lane] : 0ull;
  for (int ib = 0; ib < 3000; ib += SCAN_DEPTH) {
    #pragma unroll
    for (int d = 0; d < SCAN_DEPTH; d++) {
      const int i = ib + d;
      const unsigned long long row = buf[d];
      const int pf = i + SCAN_DEPTH;
      buf[d] = (ld && pf < 3000) ? srow[(size_t)pf * 47 + lane] : 0ull;
      const unsigned long long aw = __shfl(alive, i >> 6);
      if ((aw >> (i & 63)) & 1ull) alive &= ~row;
    }
  }
  int c = __popcll(alive);
  int pre = c;
  #pragma unroll
  for (int off = 1; off < 64; off <<= 1) {
    int t2 = __shfl_up(pre, off);
    if (lane >= off) pre += t2;
  }
  const int excl = pre - c;
  const int tot = __shfl(pre, 63);
  float4* rois4 = (float4*)(out + 540000);
  unsigned long long a = alive;
  int r = excl;
  while (a) {
    int b = __ffsll((unsigned long long)a) - 1;
    a &= (a - 1);
    if (r < 300) {
      int i = lane * 64 + b;
      const double* bb = sBoxD + ((size_t)n * 3000 + i) * 4;
      rois4[n * 300 + r] = make_float4((float)bb[0], (float)bb[1],
                                       (float)bb[2], (float)bb[3]);
    }
    r++;
  }
  for (int k = tot + lane; k < 300; k += 64)
    rois4[n * 300 + k] = make_float4(0, 0, 0, 0);
  for (int k = lane; k < 300; k += 64)
    out[544800 + n * 300 + k] = (float)n;
}

// ======================= launch =======================
extern "C" void kernel_launch(void* const* d_in, const int* in_sizes, int n_in,
                              void* d_out, int out_size, void* d_ws, size_t ws_size,
                              hipStream_t stream) {
  const float* x        = (const float*)d_in[0];
  const float* conv1_w  = (const float*)d_in[1];
  const float* conv1_b  = (const float*)d_in[2];
  const float* loc_w    = (const float*)d_in[3];
  const float* loc_b    = (const float*)d_in[4];
  const float* score_w  = (const float*)d_in[5];
  const float* score_b  = (const float*)d_in[6];
  const int*   img_h    = (const int*)d_in[7];
  const int*   img_w    = (const int*)d_in[8];
  float* out = (float*)d_out;
  char* ws = (char*)d_ws;

  // live ranges: featD conv->heads only; then its region is recycled.
  double* featD  = (double*)(ws);                  // [0, 40,960,000)
  double* locD   = (double*)(ws + 40960000);       // +2,880,000
  double* scoreD = (double*)(ws + 43840000);       // +1,440,000 -> 45,280,000
  // aliases into featD's dead region (all used strictly after heads_kernel):
  double* roiD   = (double*)(ws);                  // [0, 2,880,000)
  double* selD   = (double*)(ws + 2880000);        // +720,000
  double* sBoxD  = (double*)(ws + 3600000);        // +384,000
  int*    sValid = (int*)(ws + 4000000);           // +48,000
  unsigned long long* sup = (unsigned long long*)(ws + 4100000);  // +4,512,000
  unsigned* hist   = (unsigned*)(ws + 8700000);    // +1,048,576
  unsigned* cnt    = (unsigned*)(ws + 9750000);    // +16
  unsigned* thrP   = (unsigned*)(ws + 9751040);    // +16
  int*      candIdx= (int*)(ws + 9752000);         // +360,000
  double*   candS  = (double*)(ws + 10200000);     // +720,000 -> 10,920,000

  conv3x3_kernel<<<dim3(50, 8, 4), 256, 0, stream>>>(x, conv1_w, conv1_b, featD);
  heads_init_kernel<<<2110, 256, 0, stream>>>(loc_b, score_b, locD, scoreD);
  heads_kernel<<<dim3(10, 8, 4), 256, 0, stream>>>(featD, loc_w, score_w, locD, scoreD);
  zero_kernel<<<1024, 256, 0, stream>>>(hist, sValid, cnt);
  prep_kernel<<<dim3(88, 4), 256, 0, stream>>>(locD, scoreD, img_h, img_w,
                                               roiD, selD, hist, out);
  thresh_kernel<<<4, 256, 0, stream>>>(hist, thrP);
  compact_kernel<<<dim3(88, 4), 256, 0, stream>>>(selD, thrP, cnt, candIdx, candS);
  crank_kernel<<<dim3(88, 4), 256, 0, stream>>>(cnt, candIdx, candS, roiD, sBoxD, sValid);
  supmat_kernel<<<dim3(47, 47, 4), 64, 0, stream>>>(sBoxD, sup);
  nms_scan_kernel<<<4, 64, 0, stream>>>(sBoxD, sValid, sup, out);
}